// Round 1
// baseline (5150.148 us; speedup 1.0000x reference)
//
#include <hip/hip_runtime.h>
#include <math.h>

#define LRELU(y) ((y) > 0.f ? (y) : 0.01f * (y))
__device__ __constant__ float BNS = 0.99999500003749969f; // 1/sqrt(1+1e-5)

// ---------------------------------------------------------------------------
// prep: x (128,3,300,25,2) -> dm (256,3,299,25), x0 (256,3,25)
// xm[nm][c][t][v] = x[n][c][t][v][m]*s[ch] + b[ch], ch = m*75+v*3+c, nm=n*2+m
// ---------------------------------------------------------------------------
__global__ __launch_bounds__(256) void prep_kernel(
    const float* __restrict__ x, const float* __restrict__ g,
    const float* __restrict__ b, float* __restrict__ dm,
    float* __restrict__ x0) {
  int idx = blockIdx.x * 256 + threadIdx.x;  // (nm, c, t[0,300), v)
  if (idx >= 256 * 3 * 300 * 25) return;
  int v = idx % 25;
  int t = (idx / 25) % 300;
  int c = (idx / (25 * 300)) % 3;
  int nm = idx / (25 * 300 * 3);
  int n = nm >> 1, m = nm & 1;
  int ch = m * 75 + v * 3 + c;
  float s = g[ch] * BNS, bb = b[ch];
  long xi = (((long)(n * 3 + c) * 300 + t) * 25 + v) * 2 + m;
  float xm_t = x[xi] * s + bb;
  if (t == 0) x0[(nm * 3 + c) * 25 + v] = xm_t;
  if (t < 299) {
    float xm_t1 = x[xi + 50] * s + bb;  // t+1 stride = V*M = 50
    dm[((nm * 3 + c) * 299 + t) * 25 + v] = xm_t1 - xm_t;
  }
}

// ---------------------------------------------------------------------------
// z flags: z[nm][t] = all(dm[nm,:,t,:]==0) for t<299, z[nm][299]=0
// ---------------------------------------------------------------------------
__global__ __launch_bounds__(256) void zflag_kernel(
    const float* __restrict__ dm, unsigned char* __restrict__ z) {
  int idx = blockIdx.x * 256 + threadIdx.x;  // (nm, t[0,300))
  if (idx >= 256 * 300) return;
  int t = idx % 300;
  int nm = idx / 300;
  unsigned char zz = 0;
  if (t < 299) {
    zz = 1;
    for (int c = 0; c < 3 && zz; ++c)
      for (int v = 0; v < 25; ++v)
        if (dm[((nm * 3 + c) * 299 + t) * 25 + v] != 0.f) { zz = 0; break; }
  }
  z[nm * 300 + t] = zz;
}

// ---------------------------------------------------------------------------
// direct conv, stride 2, pad 1, 3x3, fused bias + BN + lrelu
// in (256,IC,H,W), w (OC,IC,3,3), out (256,OC,OH,OW)
// ---------------------------------------------------------------------------
template <int IC>
__global__ __launch_bounds__(256) void conv_s2_kernel(
    const float* __restrict__ in, const float* __restrict__ w,
    const float* __restrict__ cb, const float* __restrict__ bg,
    const float* __restrict__ bnb, float* __restrict__ out,
    int OC, int H, int W, int OH, int OW) {
  int idx = blockIdx.x * 256 + threadIdx.x;
  if (idx >= 256 * OC * OH * OW) return;
  int ow = idx % OW;
  int oh = (idx / OW) % OH;
  int oc = (idx / (OW * OH)) % OC;
  int nm = idx / (OW * OH * OC);
  const float* inb = in + (long)nm * IC * H * W;
  const float* wb = w + oc * IC * 9;
  float acc = 0.f;
  for (int kh = 0; kh < 3; ++kh) {
    int ih = 2 * oh + kh - 1;
    if (ih < 0 || ih >= H) continue;
    for (int kw = 0; kw < 3; ++kw) {
      int iw = 2 * ow + kw - 1;
      if (iw < 0 || iw >= W) continue;
#pragma unroll
      for (int ic = 0; ic < IC; ++ic)
        acc += inb[(ic * H + ih) * W + iw] * wb[ic * 9 + kh * 3 + kw];
    }
  }
  float y = (acc + cb[oc]) * (bg[oc] * BNS) + bnb[oc];
  out[idx] = LRELU(y);
}

// ---------------------------------------------------------------------------
// transposed conv (gather form), stride 2, pad 1, 3x3: oh = 2*ih + kh - 1
// in (256,IC,IH,IW), w (IC,OC,3,3), fused bias + BN + lrelu
// ---------------------------------------------------------------------------
template <int IC>
__global__ __launch_bounds__(256) void convt_kernel(
    const float* __restrict__ in, const float* __restrict__ w,
    const float* __restrict__ cb, const float* __restrict__ bg,
    const float* __restrict__ bnb, float* __restrict__ out,
    int OC, int IH, int IW, int OH, int OW) {
  int idx = blockIdx.x * 256 + threadIdx.x;
  if (idx >= 256 * OC * OH * OW) return;
  int ow = idx % OW;
  int oh = (idx / OW) % OH;
  int oc = (idx / (OW * OH)) % OC;
  int nm = idx / (OW * OH * OC);
  const float* inb = in + (long)nm * IC * IH * IW;
  float acc = 0.f;
  for (int kh = 0; kh < 3; ++kh) {
    int th = oh + 1 - kh;
    if (th & 1) continue;          // odd (incl. th=-1) -> no tap
    int ih = th >> 1;
    if (ih < 0 || ih >= IH) continue;
    for (int kw = 0; kw < 3; ++kw) {
      int tw = ow + 1 - kw;
      if (tw & 1) continue;
      int iw = tw >> 1;
      if (iw < 0 || iw >= IW) continue;
#pragma unroll
      for (int ic = 0; ic < IC; ++ic)
        acc += inb[(ic * IH + ih) * IW + iw] * w[((ic * OC + oc) * 3 + kh) * 3 + kw];
    }
  }
  float y = (acc + cb[oc]) * (bg[oc] * BNS) + bnb[oc];
  out[idx] = LRELU(y);
}

// ---------------------------------------------------------------------------
// convT3: 16->3, outpad (0,1), fused tanh, output trimmed to (256,3,300,25)
// in (256,16,152,16), w (16,3,3,3)
// ---------------------------------------------------------------------------
__global__ __launch_bounds__(256) void convt3_kernel(
    const float* __restrict__ in, const float* __restrict__ w,
    const float* __restrict__ cb, float* __restrict__ out) {
  int idx = blockIdx.x * 256 + threadIdx.x;  // (nm, c, t[0,300), v[0,25))
  if (idx >= 256 * 3 * 300 * 25) return;
  int v = idx % 25;
  int t = (idx / 25) % 300;
  int c = (idx / (25 * 300)) % 3;
  int nm = idx / (25 * 300 * 3);
  const float* inb = in + (long)nm * 16 * 152 * 16;
  float acc = 0.f;
  for (int kh = 0; kh < 3; ++kh) {
    int th = t + 1 - kh;
    if (th & 1) continue;
    int ih = th >> 1;
    if (ih < 0 || ih >= 152) continue;
    for (int kw = 0; kw < 3; ++kw) {
      int tw = v + 1 - kw;
      if (tw & 1) continue;
      int iw = tw >> 1;
      if (iw < 0 || iw >= 16) continue;
#pragma unroll
      for (int ic = 0; ic < 16; ++ic)
        acc += inb[(ic * 152 + ih) * 16 + iw] * w[((ic * 3 + c) * 3 + kh) * 3 + kw];
    }
  }
  out[idx] = tanhf(acc + cb[c]);
}

// ---------------------------------------------------------------------------
// FC: out[m][n] = lrelu(sum_k A[m][k]*W[n][k] + bias[n])
// A (256,K) row-major, W (N,K) row-major. 32x32 tile / block, 256 threads.
// ---------------------------------------------------------------------------
__global__ __launch_bounds__(256) void fc_kernel(
    const float* __restrict__ A, const float* __restrict__ W,
    const float* __restrict__ bias, float* __restrict__ out, int K, int Ncols) {
  __shared__ float As[32][33];
  __shared__ float Ws[32][33];
  int m0 = blockIdx.x * 32;
  int n0 = blockIdx.y * 32;
  int tid = threadIdx.x;
  int tm = (tid >> 4) << 1;
  int tn = (tid & 15) << 1;
  float acc00 = 0, acc01 = 0, acc10 = 0, acc11 = 0;
  for (int k0 = 0; k0 < K; k0 += 32) {
#pragma unroll
    for (int i = 0; i < 4; ++i) {
      int e = tid + i * 256;
      int r = e >> 5, kk = e & 31;
      As[r][kk] = A[(m0 + r) * K + k0 + kk];
      Ws[r][kk] = W[(long)(n0 + r) * K + k0 + kk];
    }
    __syncthreads();
#pragma unroll
    for (int kk = 0; kk < 32; ++kk) {
      float a0 = As[tm][kk], a1 = As[tm + 1][kk];
      float b0 = Ws[tn][kk], b1 = Ws[tn + 1][kk];
      acc00 += a0 * b0; acc01 += a0 * b1;
      acc10 += a1 * b0; acc11 += a1 * b1;
    }
    __syncthreads();
  }
  float bn0 = bias[n0 + tn], bn1 = bias[n0 + tn + 1];
  out[(m0 + tm) * Ncols + n0 + tn] = LRELU(acc00 + bn0);
  out[(m0 + tm) * Ncols + n0 + tn + 1] = LRELU(acc01 + bn1);
  out[(m0 + tm + 1) * Ncols + n0 + tn] = LRELU(acc10 + bn0);
  out[(m0 + tm + 1) * Ncols + n0 + tn + 1] = LRELU(acc11 + bn1);
}

// ---------------------------------------------------------------------------
// segmented scan over t: fin_t = z_t ? 0 : d_t + fin_{t-1}; d_0 = xm0
// dec (256,3,300,25) -> out (128,3,300,25,2)
// ---------------------------------------------------------------------------
__global__ __launch_bounds__(256) void scan_kernel(
    const float* __restrict__ dec, const float* __restrict__ x0,
    const unsigned char* __restrict__ z, float* __restrict__ out) {
  int idx = blockIdx.x * 256 + threadIdx.x;  // (nm, c, v)
  if (idx >= 256 * 75) return;
  int v = idx % 25;
  int c = (idx / 25) % 3;
  int nm = idx / 75;
  int n = nm >> 1, m = nm & 1;
  const float* db = dec + ((long)(nm * 3 + c) * 300) * 25 + v;
  const unsigned char* zb = z + nm * 300;
  float* ob = out + (((long)(n * 3 + c) * 300) * 25 + v) * 2 + m;
  float x0v = x0[(nm * 3 + c) * 25 + v];
  float carry = 0.f;
  for (int t0 = 0; t0 < 300; t0 += 10) {
    float vals[10];
#pragma unroll
    for (int i = 0; i < 10; ++i) vals[i] = db[(t0 + i) * 25];
#pragma unroll
    for (int i = 0; i < 10; ++i) {
      int t = t0 + i;
      float d = (t == 0) ? x0v : vals[i];
      carry = zb[t] ? 0.f : (d + carry);
      ob[(long)t * 50] = carry;
    }
  }
}

// ---------------------------------------------------------------------------
extern "C" void kernel_launch(void* const* d_in, const int* in_sizes, int n_in,
                              void* d_out, int out_size, void* d_ws, size_t ws_size,
                              hipStream_t stream) {
  const float* x     = (const float*)d_in[0];
  const float* dbn_g = (const float*)d_in[1];
  const float* dbn_b = (const float*)d_in[2];
  const float* c1_w  = (const float*)d_in[3];
  const float* c1_b  = (const float*)d_in[4];
  const float* bn1_g = (const float*)d_in[5];
  const float* bn1_b = (const float*)d_in[6];
  const float* c2_w  = (const float*)d_in[7];
  const float* c2_b  = (const float*)d_in[8];
  const float* bn2_g = (const float*)d_in[9];
  const float* bn2_b = (const float*)d_in[10];
  const float* c3_w  = (const float*)d_in[11];
  const float* c3_b  = (const float*)d_in[12];
  const float* bn3_g = (const float*)d_in[13];
  const float* bn3_b = (const float*)d_in[14];
  const float* fc1_w = (const float*)d_in[15];
  const float* fc1_b = (const float*)d_in[16];
  const float* fc2_w = (const float*)d_in[17];
  const float* fc2_b = (const float*)d_in[18];
  const float* fc3_w = (const float*)d_in[19];
  const float* fc3_b = (const float*)d_in[20];
  const float* fc4_w = (const float*)d_in[21];
  const float* fc4_b = (const float*)d_in[22];
  const float* ct1_w = (const float*)d_in[23];
  const float* ct1_b = (const float*)d_in[24];
  const float* bn4_g = (const float*)d_in[25];
  const float* bn4_b = (const float*)d_in[26];
  const float* ct2_w = (const float*)d_in[27];
  const float* ct2_b = (const float*)d_in[28];
  const float* bn5_g = (const float*)d_in[29];
  const float* bn5_b = (const float*)d_in[30];
  const float* ct3_w = (const float*)d_in[31];
  const float* ct3_b = (const float*)d_in[32];
  float* out = (float*)d_out;

  // workspace layout
  unsigned char* zbuf = (unsigned char*)d_ws;              // 76800 bytes
  float* fbase = (float*)((char*)d_ws + 131072);
  float* x0 = fbase;                                       // 19200
  float* S1 = fbase + 19200;                               // 5,760,000
  float* S2 = S1 + 5760000;                                // 7,987,200
  float* S3 = S2 + 7987200;                                // 9,961,472

  float* dm   = S1;
  float* c1o  = S2;
  float* c2o  = S1;
  float* c3o  = S2;
  float* f1   = S1;
  float* f2   = S1 + 300000;
  float* f3   = S1 + 400000;
  float* f4   = S1 + 700000;
  float* ct1o = S2;
  float* ct2o = S3;
  float* ct3o = S1;

  prep_kernel<<<22500, 256, 0, stream>>>(x, dbn_g, dbn_b, dm, x0);
  zflag_kernel<<<300, 256, 0, stream>>>(dm, zbuf);
  conv_s2_kernel<3><<<31200, 256, 0, stream>>>(dm, c1_w, c1_b, bn1_g, bn1_b, c1o,
                                               16, 299, 25, 150, 13);
  conv_s2_kernel<16><<<16800, 256, 0, stream>>>(c1o, c2_w, c2_b, bn2_g, bn2_b, c2o,
                                                32, 150, 13, 75, 7);
  conv_s2_kernel<32><<<9728, 256, 0, stream>>>(c2o, c3_w, c3_b, bn3_g, bn3_b, c3o,
                                               64, 75, 7, 38, 4);
  fc_kernel<<<dim3(8, 32), 256, 0, stream>>>(c3o, fc1_w, fc1_b, f1, 9728, 1024);
  fc_kernel<<<dim3(8, 4), 256, 0, stream>>>(f1, fc2_w, fc2_b, f2, 1024, 128);
  fc_kernel<<<dim3(8, 32), 256, 0, stream>>>(f2, fc3_w, fc3_b, f3, 128, 1024);
  fc_kernel<<<dim3(8, 304), 256, 0, stream>>>(f3, fc4_w, fc4_b, f4, 1024, 9728);
  convt_kernel<64><<<19456, 256, 0, stream>>>(f4, ct1_w, ct1_b, bn4_g, bn4_b, ct1o,
                                              32, 38, 4, 76, 8);
  convt_kernel<32><<<38912, 256, 0, stream>>>(ct1o, ct2_w, ct2_b, bn5_g, bn5_b, ct2o,
                                              16, 76, 8, 152, 16);
  convt3_kernel<<<22500, 256, 0, stream>>>(ct2o, ct3_w, ct3_b, ct3o);
  scan_kernel<<<75, 256, 0, stream>>>(ct3o, x0, zbuf, out);
}

// Round 2
// 1911.024 us; speedup vs baseline: 2.6950x; 2.6950x over previous
//
#include <hip/hip_runtime.h>
#include <math.h>

#define LRELU(y) ((y) > 0.f ? (y) : 0.01f * (y))
__device__ __constant__ float BNS = 0.99999500003749969f; // 1/sqrt(1+1e-5)

// ---------------------------------------------------------------------------
// prep: x (128,3,300,25,2) -> dm (256,3,299,25), x0 (256,3,25)
// ---------------------------------------------------------------------------
__global__ __launch_bounds__(256) void prep_kernel(
    const float* __restrict__ x, const float* __restrict__ g,
    const float* __restrict__ b, float* __restrict__ dm,
    float* __restrict__ x0) {
  int idx = blockIdx.x * 256 + threadIdx.x;  // (nm, c, t[0,300), v)
  if (idx >= 256 * 3 * 300 * 25) return;
  int v = idx % 25;
  int t = (idx / 25) % 300;
  int c = (idx / (25 * 300)) % 3;
  int nm = idx / (25 * 300 * 3);
  int n = nm >> 1, m = nm & 1;
  int ch = m * 75 + v * 3 + c;
  float s = g[ch] * BNS, bb = b[ch];
  long xi = (((long)(n * 3 + c) * 300 + t) * 25 + v) * 2 + m;
  float xm_t = x[xi] * s + bb;
  if (t == 0) x0[(nm * 3 + c) * 25 + v] = xm_t;
  if (t < 299) {
    float xm_t1 = x[xi + 50] * s + bb;
    dm[((nm * 3 + c) * 299 + t) * 25 + v] = xm_t1 - xm_t;
  }
}

// ---------------------------------------------------------------------------
// z flags
// ---------------------------------------------------------------------------
__global__ __launch_bounds__(256) void zflag_kernel(
    const float* __restrict__ dm, unsigned char* __restrict__ z) {
  int idx = blockIdx.x * 256 + threadIdx.x;  // (nm, t)
  if (idx >= 256 * 300) return;
  int t = idx % 300;
  int nm = idx / 300;
  unsigned char zz = 0;
  if (t < 299) {
    zz = 1;
    for (int c = 0; c < 3 && zz; ++c)
      for (int v = 0; v < 25; ++v)
        if (dm[((nm * 3 + c) * 299 + t) * 25 + v] != 0.f) { zz = 0; break; }
  }
  z[nm * 300 + t] = zz;
}

// ---------------------------------------------------------------------------
// Tiled direct conv, stride 2, pad 1, 3x3. Input tile + weights in LDS.
// Each work item = ACC consecutive ocs at one (oh,ow). bias+BN+lrelu fused.
// in (256,IC,H,W), w (OC,IC,3,3), out (256,OC,OH,OW)
// grid: (NTILE * OC/OCB, 256)
// ---------------------------------------------------------------------------
template <int IC, int OC, int OCB, int ACC, int H, int W, int OH, int OW,
          int TOH, int NTILE>
__global__ __launch_bounds__(256) void conv_tiled_kernel(
    const float* __restrict__ in, const float* __restrict__ w,
    const float* __restrict__ cb, const float* __restrict__ bg,
    const float* __restrict__ bnb, float* __restrict__ out) {
  constexpr int IHT = 2 * TOH + 1;
  constexpr int RL = W + 2;  // padded cols, col = iw+1
  __shared__ __align__(16) float in_s[IC * IHT * RL];
  __shared__ __align__(16) float w_s[9 * IC * OCB];
  int bx = blockIdx.x;
  int nm = blockIdx.y;
  int tile = bx % NTILE;
  int oc0 = (bx / NTILE) * OCB;
  int oh0 = tile * TOH;
  int ih0 = 2 * oh0 - 1;
  const float* inb = in + (long)nm * IC * H * W;
  for (int e = threadIdx.x; e < IC * IHT * RL; e += 256) {
    int c = e % RL;
    int r = (e / RL) % IHT;
    int ic = e / (RL * IHT);
    int ih = ih0 + r, iw = c - 1;
    float v = 0.f;
    if (ih >= 0 && ih < H && iw >= 0 && iw < W) v = inb[(ic * H + ih) * W + iw];
    in_s[e] = v;
  }
  for (int e = threadIdx.x; e < 9 * IC * OCB; e += 256) {
    int ocl = e % OCB;
    int ic = (e / OCB) % IC;
    int khw = e / (OCB * IC);
    int kh = khw / 3, kw = khw % 3;
    w_s[e] = w[(((oc0 + ocl) * IC + ic) * 3 + kh) * 3 + kw];
  }
  __syncthreads();
  constexpr int NPOS = TOH * OW;
  constexpr int NWI = NPOS * (OCB / ACC);
  for (int wi = threadIdx.x; wi < NWI; wi += 256) {
    int pos = wi % NPOS;
    int jb = (wi / NPOS) * ACC;
    int ow = pos % OW;
    int oh_l = pos / OW;
    int oh = oh0 + oh_l;
    if (oh >= OH) continue;
    float acc[ACC];
#pragma unroll
    for (int j = 0; j < ACC; ++j) acc[j] = 0.f;
    for (int kh = 0; kh < 3; ++kh) {
      int r = 2 * oh_l + kh;
      for (int kw = 0; kw < 3; ++kw) {
        int cc = 2 * ow + kw;
        const float* ip = &in_s[r * RL + cc];
        const float* wp = &w_s[(kh * 3 + kw) * IC * OCB + jb];
        for (int ic = 0; ic < IC; ++ic) {
          float a = ip[ic * IHT * RL];
#pragma unroll
          for (int j = 0; j < ACC; ++j) acc[j] += a * wp[ic * OCB + j];
        }
      }
    }
#pragma unroll
    for (int j = 0; j < ACC; ++j) {
      int oc = oc0 + jb + j;
      float y = (acc[j] + cb[oc]) * (bg[oc] * BNS) + bnb[oc];
      out[((long)nm * OC + oc) * OH * OW + oh * OW + ow] = LRELU(y);
    }
  }
}

// ---------------------------------------------------------------------------
// Tiled transposed conv (gather), stride 2, pad 1, 3x3. TOH must be even.
// in (256,IC,IH,IW), w (IC,OC,3,3), out (256,OC,OH,OW); bias+BN+lrelu fused.
// grid: (NTILE, 256)
// ---------------------------------------------------------------------------
template <int IC, int OC, int ACC, int IH, int IW, int OH, int OW, int TOH,
          int NTILE>
__global__ __launch_bounds__(256) void convt_tiled_kernel(
    const float* __restrict__ in, const float* __restrict__ w,
    const float* __restrict__ cb, const float* __restrict__ bg,
    const float* __restrict__ bnb, float* __restrict__ out) {
  constexpr int IHT = TOH / 2 + 1;
  constexpr int RL = IW + 1;  // pad right col (zero)
  __shared__ __align__(16) float in_s[IC * IHT * RL];
  __shared__ __align__(16) float w_s[9 * IC * OC];
  int nm = blockIdx.y;
  int oh0 = blockIdx.x * TOH;
  int ihb = oh0 / 2;
  const float* inb = in + (long)nm * IC * IH * IW;
  for (int e = threadIdx.x; e < IC * IHT * RL; e += 256) {
    int c = e % RL;
    int r = (e / RL) % IHT;
    int ic = e / (RL * IHT);
    int ih = ihb + r;
    float v = 0.f;
    if (c < IW && ih < IH) v = inb[(ic * IH + ih) * IW + c];
    in_s[e] = v;
  }
  for (int e = threadIdx.x; e < 9 * IC * OC; e += 256) {
    int ocl = e % OC;
    int ic = (e / OC) % IC;
    int khw = e / (OC * IC);
    int kh = khw / 3, kw = khw % 3;
    w_s[e] = w[((ic * OC + ocl) * 3 + kh) * 3 + kw];
  }
  __syncthreads();
  constexpr int NPOS = TOH * OW;
  constexpr int NWI = NPOS * (OC / ACC);
  for (int wi = threadIdx.x; wi < NWI; wi += 256) {
    int pos = wi % NPOS;
    int jb = (wi / NPOS) * ACC;
    int ow = pos % OW;
    int oh = oh0 + pos / OW;
    if (oh >= OH) continue;
    float acc[ACC];
#pragma unroll
    for (int j = 0; j < ACC; ++j) acc[j] = 0.f;
    for (int kh = 0; kh < 3; ++kh) {
      int th = oh + 1 - kh;
      if (th & 1) continue;
      int r = (th >> 1) - ihb;
      for (int kw = 0; kw < 3; ++kw) {
        int tw = ow + 1 - kw;
        if (tw & 1) continue;
        int c = tw >> 1;
        const float* ip = &in_s[r * RL + c];
        const float* wp = &w_s[(kh * 3 + kw) * IC * OC + jb];
        for (int ic = 0; ic < IC; ++ic) {
          float a = ip[ic * IHT * RL];
#pragma unroll
          for (int j = 0; j < ACC; ++j) acc[j] += a * wp[ic * OC + j];
        }
      }
    }
#pragma unroll
    for (int j = 0; j < ACC; ++j) {
      int oc = jb + j;
      float y = (acc[j] + cb[oc]) * (bg[oc] * BNS) + bnb[oc];
      out[((long)nm * OC + oc) * OH * OW + oh * OW + ow] = LRELU(y);
    }
  }
}

// ---------------------------------------------------------------------------
// convT3 tiled: 16->3, tanh fused, output trimmed to (256,3,300,25)
// in (256,16,152,16), w (16,3,3,3). grid (3, 256), TOH=100.
// ---------------------------------------------------------------------------
__global__ __launch_bounds__(256) void convt3_tiled_kernel(
    const float* __restrict__ in, const float* __restrict__ w,
    const float* __restrict__ cb, float* __restrict__ out) {
  constexpr int IC = 16, IH = 152, IW = 16, TOH = 100, IHT = 51, RL = 17;
  __shared__ __align__(16) float in_s[IC * IHT * RL];
  __shared__ float w_s[9 * IC * 3];
  int nm = blockIdx.y;
  int oh0 = blockIdx.x * TOH;
  int ihb = oh0 / 2;
  const float* inb = in + (long)nm * IC * IH * IW;
  for (int e = threadIdx.x; e < IC * IHT * RL; e += 256) {
    int c = e % RL;
    int r = (e / RL) % IHT;
    int ic = e / (RL * IHT);
    int ih = ihb + r;
    float v = 0.f;
    if (c < IW && ih < IH) v = inb[(ic * IH + ih) * IW + c];
    in_s[e] = v;
  }
  for (int e = threadIdx.x; e < 9 * IC * 3; e += 256) {
    int ocl = e % 3;
    int ic = (e / 3) % IC;
    int khw = e / (3 * IC);
    int kh = khw / 3, kw = khw % 3;
    w_s[e] = w[((ic * 3 + ocl) * 3 + kh) * 3 + kw];
  }
  __syncthreads();
  for (int wi = threadIdx.x; wi < TOH * 25; wi += 256) {
    int v = wi % 25;
    int t = oh0 + wi / 25;
    if (t >= 300) continue;
    float acc[3] = {0.f, 0.f, 0.f};
    for (int kh = 0; kh < 3; ++kh) {
      int th = t + 1 - kh;
      if (th & 1) continue;
      int r = (th >> 1) - ihb;
      for (int kw = 0; kw < 3; ++kw) {
        int tw = v + 1 - kw;
        if (tw & 1) continue;
        int c = tw >> 1;
        const float* ip = &in_s[r * RL + c];
        const float* wp = &w_s[(kh * 3 + kw) * IC * 3];
        for (int ic = 0; ic < IC; ++ic) {
          float a = ip[ic * IHT * RL];
#pragma unroll
          for (int j = 0; j < 3; ++j) acc[j] += a * wp[ic * 3 + j];
        }
      }
    }
#pragma unroll
    for (int j = 0; j < 3; ++j)
      out[((long)(nm * 3 + j) * 300 + t) * 25 + v] = tanhf(acc[j] + cb[j]);
  }
}

// ---------------------------------------------------------------------------
// FC: out[m][n] = lrelu(sum_k A[m][k]*W[n][k] + bias[n])
// 32x32 tile, transposed LDS ([kk][m], pad 34) for b64 inner reads.
// ---------------------------------------------------------------------------
__global__ __launch_bounds__(256) void fc_kernel(
    const float* __restrict__ A, const float* __restrict__ W,
    const float* __restrict__ bias, float* __restrict__ out, int K, int Ncols) {
  __shared__ __align__(16) float As[32][34];  // [kk][m]
  __shared__ __align__(16) float Ws[32][34];  // [kk][n]
  int m0 = blockIdx.x * 32;
  int n0 = blockIdx.y * 32;
  int tid = threadIdx.x;
  int tm = (tid >> 4) << 1;
  int tn = (tid & 15) << 1;
  float acc00 = 0, acc01 = 0, acc10 = 0, acc11 = 0;
  for (int k0 = 0; k0 < K; k0 += 32) {
#pragma unroll
    for (int i = 0; i < 4; ++i) {
      int e = tid + i * 256;
      int r = e >> 5, kk = e & 31;
      As[kk][r] = A[(m0 + r) * K + k0 + kk];
      Ws[kk][r] = W[(long)(n0 + r) * K + k0 + kk];
    }
    __syncthreads();
#pragma unroll
    for (int kk = 0; kk < 32; ++kk) {
      float2 a = *(const float2*)&As[kk][tm];
      float2 b = *(const float2*)&Ws[kk][tn];
      acc00 += a.x * b.x; acc01 += a.x * b.y;
      acc10 += a.y * b.x; acc11 += a.y * b.y;
    }
    __syncthreads();
  }
  float bn0 = bias[n0 + tn], bn1 = bias[n0 + tn + 1];
  out[(m0 + tm) * Ncols + n0 + tn] = LRELU(acc00 + bn0);
  out[(m0 + tm) * Ncols + n0 + tn + 1] = LRELU(acc01 + bn1);
  out[(m0 + tm + 1) * Ncols + n0 + tn] = LRELU(acc10 + bn0);
  out[(m0 + tm + 1) * Ncols + n0 + tn + 1] = LRELU(acc11 + bn1);
}

// ---------------------------------------------------------------------------
// segmented scan over t
// ---------------------------------------------------------------------------
__global__ __launch_bounds__(256) void scan_kernel(
    const float* __restrict__ dec, const float* __restrict__ x0,
    const unsigned char* __restrict__ z, float* __restrict__ out) {
  int idx = blockIdx.x * 256 + threadIdx.x;  // (nm, c, v)
  if (idx >= 256 * 75) return;
  int v = idx % 25;
  int c = (idx / 25) % 3;
  int nm = idx / 75;
  int n = nm >> 1, m = nm & 1;
  const float* db = dec + ((long)(nm * 3 + c) * 300) * 25 + v;
  const unsigned char* zb = z + nm * 300;
  float* ob = out + (((long)(n * 3 + c) * 300) * 25 + v) * 2 + m;
  float x0v = x0[(nm * 3 + c) * 25 + v];
  float carry = 0.f;
  for (int t0 = 0; t0 < 300; t0 += 10) {
    float vals[10];
#pragma unroll
    for (int i = 0; i < 10; ++i) vals[i] = db[(t0 + i) * 25];
#pragma unroll
    for (int i = 0; i < 10; ++i) {
      int t = t0 + i;
      float d = (t == 0) ? x0v : vals[i];
      carry = zb[t] ? 0.f : (d + carry);
      ob[(long)t * 50] = carry;
    }
  }
}

// ---------------------------------------------------------------------------
extern "C" void kernel_launch(void* const* d_in, const int* in_sizes, int n_in,
                              void* d_out, int out_size, void* d_ws, size_t ws_size,
                              hipStream_t stream) {
  const float* x     = (const float*)d_in[0];
  const float* dbn_g = (const float*)d_in[1];
  const float* dbn_b = (const float*)d_in[2];
  const float* c1_w  = (const float*)d_in[3];
  const float* c1_b  = (const float*)d_in[4];
  const float* bn1_g = (const float*)d_in[5];
  const float* bn1_b = (const float*)d_in[6];
  const float* c2_w  = (const float*)d_in[7];
  const float* c2_b  = (const float*)d_in[8];
  const float* bn2_g = (const float*)d_in[9];
  const float* bn2_b = (const float*)d_in[10];
  const float* c3_w  = (const float*)d_in[11];
  const float* c3_b  = (const float*)d_in[12];
  const float* bn3_g = (const float*)d_in[13];
  const float* bn3_b = (const float*)d_in[14];
  const float* fc1_w = (const float*)d_in[15];
  const float* fc1_b = (const float*)d_in[16];
  const float* fc2_w = (const float*)d_in[17];
  const float* fc2_b = (const float*)d_in[18];
  const float* fc3_w = (const float*)d_in[19];
  const float* fc3_b = (const float*)d_in[20];
  const float* fc4_w = (const float*)d_in[21];
  const float* fc4_b = (const float*)d_in[22];
  const float* ct1_w = (const float*)d_in[23];
  const float* ct1_b = (const float*)d_in[24];
  const float* bn4_g = (const float*)d_in[25];
  const float* bn4_b = (const float*)d_in[26];
  const float* ct2_w = (const float*)d_in[27];
  const float* ct2_b = (const float*)d_in[28];
  const float* bn5_g = (const float*)d_in[29];
  const float* bn5_b = (const float*)d_in[30];
  const float* ct3_w = (const float*)d_in[31];
  const float* ct3_b = (const float*)d_in[32];
  float* out = (float*)d_out;

  unsigned char* zbuf = (unsigned char*)d_ws;
  float* fbase = (float*)((char*)d_ws + 131072);
  float* x0 = fbase;
  float* S1 = fbase + 19200;
  float* S2 = S1 + 5760000;
  float* S3 = S2 + 7987200;

  float* dm   = S1;
  float* c1o  = S2;
  float* c2o  = S1;
  float* c3o  = S2;
  float* f1   = S1;
  float* f2   = S1 + 300000;
  float* f3   = S1 + 400000;
  float* f4   = S1 + 700000;
  float* ct1o = S2;
  float* ct2o = S3;
  float* ct3o = S1;

  prep_kernel<<<22500, 256, 0, stream>>>(x, dbn_g, dbn_b, dm, x0);
  zflag_kernel<<<300, 256, 0, stream>>>(dm, zbuf);
  // conv1: IC=3 OC=16 H=299 W=25 -> 150x13, TOH=30, 5 tiles
  conv_tiled_kernel<3, 16, 16, 16, 299, 25, 150, 13, 30, 5>
      <<<dim3(5, 256), 256, 0, stream>>>(dm, c1_w, c1_b, bn1_g, bn1_b, c1o);
  // conv2: IC=16 OC=32 H=150 W=13 -> 75x7, TOH=38, 2 tiles
  conv_tiled_kernel<16, 32, 32, 32, 150, 13, 75, 7, 38, 2>
      <<<dim3(2, 256), 256, 0, stream>>>(c1o, c2_w, c2_b, bn2_g, bn2_b, c2o);
  // conv3: IC=32 OC=64 H=75 W=7 -> 38x4, TOH=38, 1 tile, 2 oc-halves
  conv_tiled_kernel<32, 64, 32, 16, 75, 7, 38, 4, 38, 1>
      <<<dim3(2, 256), 256, 0, stream>>>(c2o, c3_w, c3_b, bn3_g, bn3_b, c3o);
  fc_kernel<<<dim3(8, 32), 256, 0, stream>>>(c3o, fc1_w, fc1_b, f1, 9728, 1024);
  fc_kernel<<<dim3(8, 4), 256, 0, stream>>>(f1, fc2_w, fc2_b, f2, 1024, 128);
  fc_kernel<<<dim3(8, 32), 256, 0, stream>>>(f2, fc3_w, fc3_b, f3, 128, 1024);
  fc_kernel<<<dim3(8, 304), 256, 0, stream>>>(f3, fc4_w, fc4_b, f4, 1024, 9728);
  // ct1: IC=64 OC=32 (38,4)->(76,8), full tile
  convt_tiled_kernel<64, 32, 32, 38, 4, 76, 8, 76, 1>
      <<<dim3(1, 256), 256, 0, stream>>>(f4, ct1_w, ct1_b, bn4_g, bn4_b, ct1o);
  // ct2: IC=32 OC=16 (76,8)->(152,16), full tile
  convt_tiled_kernel<32, 16, 16, 76, 8, 152, 16, 152, 1>
      <<<dim3(1, 256), 256, 0, stream>>>(ct1o, ct2_w, ct2_b, bn5_g, bn5_b, ct2o);
  // ct3: IC=16 OC=3 (152,16)->(300,25) trimmed, tanh
  convt3_tiled_kernel<<<dim3(3, 256), 256, 0, stream>>>(ct2o, ct3_w, ct3_b, ct3o);
  scan_kernel<<<75, 256, 0, stream>>>(ct3o, x0, zbuf, out);
}

// Round 3
// 1276.560 us; speedup vs baseline: 4.0344x; 1.4970x over previous
//
#include <hip/hip_runtime.h>
#include <math.h>

#define LRELU(y) ((y) > 0.f ? (y) : 0.01f * (y))
__device__ __constant__ float BNS = 0.99999500003749969f; // 1/sqrt(1+1e-5)

typedef unsigned short u16;
typedef __attribute__((ext_vector_type(8))) short bf16x8;
typedef __attribute__((ext_vector_type(4))) float f32x4;

__device__ inline u16 f2b(float f) {
  union { float f; unsigned u; } x; x.f = f;
  return (u16)((x.u + 0x7FFFu + ((x.u >> 16) & 1u)) >> 16);
}
__device__ inline float b2f(u16 b) {
  union { unsigned u; float f; } x; x.u = ((unsigned)b) << 16;
  return x.f;
}
__device__ inline float ldv(const float* p) { return *p; }
__device__ inline float ldv(const u16* p) { return b2f(*p); }

// ---------------------------------------------------------------------------
// cast fp32 -> bf16, 4 elements/thread
// ---------------------------------------------------------------------------
__global__ __launch_bounds__(256) void cast_kernel(
    const float* __restrict__ s, u16* __restrict__ d, int n4) {
  int i = blockIdx.x * 256 + threadIdx.x;
  if (i >= n4) return;
  float4 v = ((const float4*)s)[i];
  ushort4 o;
  o.x = f2b(v.x); o.y = f2b(v.y); o.z = f2b(v.z); o.w = f2b(v.w);
  ((ushort4*)d)[i] = o;
}

// ---------------------------------------------------------------------------
// prep: x (128,3,300,25,2) -> dm (256,3,299,25) fp32, x0 (256,3,25) fp32
// ---------------------------------------------------------------------------
__global__ __launch_bounds__(256) void prep_kernel(
    const float* __restrict__ x, const float* __restrict__ g,
    const float* __restrict__ b, float* __restrict__ dm,
    float* __restrict__ x0) {
  int idx = blockIdx.x * 256 + threadIdx.x;  // (nm, c, t[0,300), v)
  if (idx >= 256 * 3 * 300 * 25) return;
  int v = idx % 25;
  int t = (idx / 25) % 300;
  int c = (idx / (25 * 300)) % 3;
  int nm = idx / (25 * 300 * 3);
  int n = nm >> 1, m = nm & 1;
  int ch = m * 75 + v * 3 + c;
  float s = g[ch] * BNS, bb = b[ch];
  long xi = (((long)(n * 3 + c) * 300 + t) * 25 + v) * 2 + m;
  float xm_t = x[xi] * s + bb;
  if (t == 0) x0[(nm * 3 + c) * 25 + v] = xm_t;
  if (t < 299) {
    float xm_t1 = x[xi + 50] * s + bb;
    dm[((nm * 3 + c) * 299 + t) * 25 + v] = xm_t1 - xm_t;
  }
}

// ---------------------------------------------------------------------------
// z flags on exact fp32 dm
// ---------------------------------------------------------------------------
__global__ __launch_bounds__(256) void zflag_kernel(
    const float* __restrict__ dm, unsigned char* __restrict__ z) {
  int idx = blockIdx.x * 256 + threadIdx.x;  // (nm, t)
  if (idx >= 256 * 300) return;
  int t = idx % 300;
  int nm = idx / 300;
  unsigned char zz = 0;
  if (t < 299) {
    zz = 1;
    for (int c = 0; c < 3 && zz; ++c)
      for (int v = 0; v < 25; ++v)
        if (dm[((nm * 3 + c) * 299 + t) * 25 + v] != 0.f) { zz = 0; break; }
  }
  z[nm * 300 + t] = zz;
}

// ---------------------------------------------------------------------------
// Tiled direct conv, stride 2, pad 1, 3x3. LDS input tile + weights.
// TI = float or u16(bf16) input; output bf16. ACC ocs per work item.
// grid: (NTILE * OC/OCB, 256)
// ---------------------------------------------------------------------------
template <typename TI, int IC, int OC, int OCB, int ACC, int H, int W, int OH,
          int OW, int TOH, int NTILE>
__global__ __launch_bounds__(256) void conv_tiled_kernel(
    const TI* __restrict__ in, const float* __restrict__ w,
    const float* __restrict__ cb, const float* __restrict__ bg,
    const float* __restrict__ bnb, u16* __restrict__ out) {
  constexpr int IHT = 2 * TOH + 1;
  constexpr int RL = W + 2;
  __shared__ float in_s[IC * IHT * RL];
  __shared__ float w_s[9 * IC * OCB];
  int bx = blockIdx.x;
  int nm = blockIdx.y;
  int tile = bx % NTILE;
  int oc0 = (bx / NTILE) * OCB;
  int oh0 = tile * TOH;
  int ih0 = 2 * oh0 - 1;
  const TI* inb = in + (long)nm * IC * H * W;
  for (int e = threadIdx.x; e < IC * IHT * RL; e += 256) {
    int c = e % RL;
    int r = (e / RL) % IHT;
    int ic = e / (RL * IHT);
    int ih = ih0 + r, iw = c - 1;
    float v = 0.f;
    if (ih >= 0 && ih < H && iw >= 0 && iw < W) v = ldv(&inb[(ic * H + ih) * W + iw]);
    in_s[e] = v;
  }
  for (int e = threadIdx.x; e < 9 * IC * OCB; e += 256) {
    int ocl = e % OCB;
    int ic = (e / OCB) % IC;
    int khw = e / (OCB * IC);
    int kh = khw / 3, kw = khw % 3;
    w_s[e] = w[(((oc0 + ocl) * IC + ic) * 3 + kh) * 3 + kw];
  }
  __syncthreads();
  constexpr int NPOS = TOH * OW;
  constexpr int NWI = NPOS * (OCB / ACC);
  for (int wi = threadIdx.x; wi < NWI; wi += 256) {
    int pos = wi % NPOS;
    int jb = (wi / NPOS) * ACC;
    int ow = pos % OW;
    int oh_l = pos / OW;
    int oh = oh0 + oh_l;
    if (oh >= OH) continue;
    float acc[ACC];
#pragma unroll
    for (int j = 0; j < ACC; ++j) acc[j] = 0.f;
    for (int kh = 0; kh < 3; ++kh) {
      int r = 2 * oh_l + kh;
      for (int kw = 0; kw < 3; ++kw) {
        int cc = 2 * ow + kw;
        const float* ip = &in_s[r * RL + cc];
        const float* wp = &w_s[(kh * 3 + kw) * IC * OCB + jb];
        for (int ic = 0; ic < IC; ++ic) {
          float a = ip[ic * IHT * RL];
#pragma unroll
          for (int j = 0; j < ACC; ++j) acc[j] += a * wp[ic * OCB + j];
        }
      }
    }
#pragma unroll
    for (int j = 0; j < ACC; ++j) {
      int oc = oc0 + jb + j;
      float y = (acc[j] + cb[oc]) * (bg[oc] * BNS) + bnb[oc];
      out[((long)nm * OC + oc) * OH * OW + oh * OW + ow] = f2b(LRELU(y));
    }
  }
}

// ---------------------------------------------------------------------------
// Tiled transposed conv (gather), stride 2, pad 1, 3x3. bf16 in/out.
// grid: (NTILEH * OC/OCB, 256). TOH even.
// ---------------------------------------------------------------------------
template <int IC, int OC, int OCB, int ACC, int IH, int IW, int OH, int OW,
          int TOH, int NTILEH>
__global__ __launch_bounds__(256) void convt_tiled_kernel(
    const u16* __restrict__ in, const float* __restrict__ w,
    const float* __restrict__ cb, const float* __restrict__ bg,
    const float* __restrict__ bnb, u16* __restrict__ out) {
  constexpr int IHT = TOH / 2 + 1;
  constexpr int RL = IW + 1;
  __shared__ float in_s[IC * IHT * RL];
  __shared__ float w_s[9 * IC * OCB];
  int nm = blockIdx.y;
  int tile = blockIdx.x % NTILEH;
  int oc0 = (blockIdx.x / NTILEH) * OCB;
  int oh0 = tile * TOH;
  int ihb = oh0 / 2;
  const u16* inb = in + (long)nm * IC * IH * IW;
  for (int e = threadIdx.x; e < IC * IHT * RL; e += 256) {
    int c = e % RL;
    int r = (e / RL) % IHT;
    int ic = e / (RL * IHT);
    int ih = ihb + r;
    float v = 0.f;
    if (c < IW && ih < IH) v = ldv(&inb[(ic * IH + ih) * IW + c]);
    in_s[e] = v;
  }
  for (int e = threadIdx.x; e < 9 * IC * OCB; e += 256) {
    int ocl = e % OCB;
    int ic = (e / OCB) % IC;
    int khw = e / (OCB * IC);
    int kh = khw / 3, kw = khw % 3;
    w_s[e] = w[((ic * OC + oc0 + ocl) * 3 + kh) * 3 + kw];
  }
  __syncthreads();
  constexpr int NPOS = TOH * OW;
  constexpr int NWI = NPOS * (OCB / ACC);
  for (int wi = threadIdx.x; wi < NWI; wi += 256) {
    int pos = wi % NPOS;
    int jb = (wi / NPOS) * ACC;
    int ow = pos % OW;
    int oh = oh0 + pos / OW;
    float acc[ACC];
#pragma unroll
    for (int j = 0; j < ACC; ++j) acc[j] = 0.f;
    for (int kh = 0; kh < 3; ++kh) {
      int th = oh + 1 - kh;
      if (th & 1) continue;
      int r = (th >> 1) - ihb;
      for (int kw = 0; kw < 3; ++kw) {
        int tw = ow + 1 - kw;
        if (tw & 1) continue;
        int c = tw >> 1;
        const float* ip = &in_s[r * RL + c];
        const float* wp = &w_s[(kh * 3 + kw) * IC * OCB + jb];
        for (int ic = 0; ic < IC; ++ic) {
          float a = ip[ic * IHT * RL];
#pragma unroll
          for (int j = 0; j < ACC; ++j) acc[j] += a * wp[ic * OCB + j];
        }
      }
    }
#pragma unroll
    for (int j = 0; j < ACC; ++j) {
      int oc = oc0 + jb + j;
      float y = (acc[j] + cb[oc]) * (bg[oc] * BNS) + bnb[oc];
      out[((long)nm * OC + oc) * OH * OW + oh * OW + ow] = f2b(LRELU(y));
    }
  }
}

// ---------------------------------------------------------------------------
// convT3: 16->3, tanh fused, bf16 in, fp32 out trimmed to (256,3,300,25)
// grid (4, 256), TOH=76
// ---------------------------------------------------------------------------
__global__ __launch_bounds__(256) void convt3_tiled_kernel(
    const u16* __restrict__ in, const float* __restrict__ w,
    const float* __restrict__ cb, float* __restrict__ out) {
  constexpr int IC = 16, IH = 152, IW = 16, TOH = 76, IHT = 39, RL = 17;
  __shared__ float in_s[IC * IHT * RL];
  __shared__ float w_s[9 * IC * 3];
  int nm = blockIdx.y;
  int oh0 = blockIdx.x * TOH;
  int ihb = oh0 / 2;
  const u16* inb = in + (long)nm * IC * IH * IW;
  for (int e = threadIdx.x; e < IC * IHT * RL; e += 256) {
    int c = e % RL;
    int r = (e / RL) % IHT;
    int ic = e / (RL * IHT);
    int ih = ihb + r;
    float v = 0.f;
    if (c < IW && ih < IH) v = ldv(&inb[(ic * IH + ih) * IW + c]);
    in_s[e] = v;
  }
  for (int e = threadIdx.x; e < 9 * IC * 3; e += 256) {
    int ocl = e % 3;
    int ic = (e / 3) % IC;
    int khw = e / (3 * IC);
    int kh = khw / 3, kw = khw % 3;
    w_s[e] = w[((ic * 3 + ocl) * 3 + kh) * 3 + kw];
  }
  __syncthreads();
  for (int wi = threadIdx.x; wi < TOH * 25; wi += 256) {
    int v = wi % 25;
    int t = oh0 + wi / 25;
    if (t >= 300) continue;
    float acc[3] = {0.f, 0.f, 0.f};
    for (int kh = 0; kh < 3; ++kh) {
      int th = t + 1 - kh;
      if (th & 1) continue;
      int r = (th >> 1) - ihb;
      for (int kw = 0; kw < 3; ++kw) {
        int tw = v + 1 - kw;
        if (tw & 1) continue;
        int c = tw >> 1;
        const float* ip = &in_s[r * RL + c];
        const float* wp = &w_s[(kh * 3 + kw) * IC * 3];
        for (int ic = 0; ic < IC; ++ic) {
          float a = ip[ic * IHT * RL];
#pragma unroll
          for (int j = 0; j < 3; ++j) acc[j] += a * wp[ic * 3 + j];
        }
      }
    }
#pragma unroll
    for (int j = 0; j < 3; ++j)
      out[((long)(nm * 3 + j) * 300 + t) * 25 + v] = tanhf(acc[j] + cb[j]);
  }
}

// ---------------------------------------------------------------------------
// FC via MFMA bf16: out[m][n] = lrelu_bf16(sum_k A[m][k]*W[n][k] + bias[n])
// A (256,K) bf16 row-major, Wt (N,K) bf16 row-major. Block 64x64, BK=64,
// 4 waves each 32x32 (2x2 of 16x16x32 MFMA). grid (M/64, N/64).
// ---------------------------------------------------------------------------
__global__ __launch_bounds__(256) void fc_mfma_kernel(
    const u16* __restrict__ A, const u16* __restrict__ Wt,
    const float* __restrict__ bias, u16* __restrict__ out, int K, int N) {
  __shared__ u16 As[64][72];
  __shared__ u16 Bs[64][72];
  int tid = threadIdx.x;
  int m0 = blockIdx.x * 64, n0 = blockIdx.y * 64;
  int wv = tid >> 6, lane = tid & 63;
  int lr = lane & 15, q = lane >> 4;
  int mb = (wv >> 1) * 32, nb = (wv & 1) * 32;
  f32x4 acc[2][2] = {};
  for (int k0 = 0; k0 < K; k0 += 64) {
    __syncthreads();
#pragma unroll
    for (int i = 0; i < 2; ++i) {
      int e = tid + i * 256;
      int row = e >> 3, seg = (e & 7) * 8;
      *(uint4*)&As[row][seg] = *(const uint4*)(A + (long)(m0 + row) * K + k0 + seg);
      *(uint4*)&Bs[row][seg] = *(const uint4*)(Wt + (long)(n0 + row) * K + k0 + seg);
    }
    __syncthreads();
#pragma unroll
    for (int kk = 0; kk < 64; kk += 32) {
      bf16x8 a0 = *(bf16x8*)&As[mb + lr][kk + q * 8];
      bf16x8 a1 = *(bf16x8*)&As[mb + 16 + lr][kk + q * 8];
      bf16x8 b0 = *(bf16x8*)&Bs[nb + lr][kk + q * 8];
      bf16x8 b1 = *(bf16x8*)&Bs[nb + 16 + lr][kk + q * 8];
      acc[0][0] = __builtin_amdgcn_mfma_f32_16x16x32_bf16(a0, b0, acc[0][0], 0, 0, 0);
      acc[0][1] = __builtin_amdgcn_mfma_f32_16x16x32_bf16(a0, b1, acc[0][1], 0, 0, 0);
      acc[1][0] = __builtin_amdgcn_mfma_f32_16x16x32_bf16(a1, b0, acc[1][0], 0, 0, 0);
      acc[1][1] = __builtin_amdgcn_mfma_f32_16x16x32_bf16(a1, b1, acc[1][1], 0, 0, 0);
    }
  }
#pragma unroll
  for (int mi = 0; mi < 2; ++mi)
#pragma unroll
    for (int ni = 0; ni < 2; ++ni) {
      int col = n0 + nb + ni * 16 + lr;
      float bv = bias[col];
#pragma unroll
      for (int r = 0; r < 4; ++r) {
        int row = m0 + mb + mi * 16 + q * 4 + r;
        float y = acc[mi][ni][r] + bv;
        out[(long)row * N + col] = f2b(LRELU(y));
      }
    }
}

// ---------------------------------------------------------------------------
// segmented scan over t: fin_t = z_t ? 0 : d_t + fin_{t-1}; d_0 = xm0
// ---------------------------------------------------------------------------
__global__ __launch_bounds__(256) void scan_kernel(
    const float* __restrict__ dec, const float* __restrict__ x0,
    const unsigned char* __restrict__ z, float* __restrict__ out) {
  int idx = blockIdx.x * 256 + threadIdx.x;  // (nm, c, v)
  if (idx >= 256 * 75) return;
  int v = idx % 25;
  int c = (idx / 25) % 3;
  int nm = idx / 75;
  int n = nm >> 1, m = nm & 1;
  const float* db = dec + ((long)(nm * 3 + c) * 300) * 25 + v;
  const unsigned char* zb = z + nm * 300;
  float* ob = out + (((long)(n * 3 + c) * 300) * 25 + v) * 2 + m;
  float x0v = x0[(nm * 3 + c) * 25 + v];
  float carry = 0.f;
  for (int t0 = 0; t0 < 300; t0 += 10) {
    float vals[10];
#pragma unroll
    for (int i = 0; i < 10; ++i) vals[i] = db[(t0 + i) * 25];
#pragma unroll
    for (int i = 0; i < 10; ++i) {
      int t = t0 + i;
      float d = (t == 0) ? x0v : vals[i];
      carry = zb[t] ? 0.f : (d + carry);
      ob[(long)t * 50] = carry;
    }
  }
}

// ---------------------------------------------------------------------------
extern "C" void kernel_launch(void* const* d_in, const int* in_sizes, int n_in,
                              void* d_out, int out_size, void* d_ws, size_t ws_size,
                              hipStream_t stream) {
  const float* x     = (const float*)d_in[0];
  const float* dbn_g = (const float*)d_in[1];
  const float* dbn_b = (const float*)d_in[2];
  const float* c1_w  = (const float*)d_in[3];
  const float* c1_b  = (const float*)d_in[4];
  const float* bn1_g = (const float*)d_in[5];
  const float* bn1_b = (const float*)d_in[6];
  const float* c2_w  = (const float*)d_in[7];
  const float* c2_b  = (const float*)d_in[8];
  const float* bn2_g = (const float*)d_in[9];
  const float* bn2_b = (const float*)d_in[10];
  const float* c3_w  = (const float*)d_in[11];
  const float* c3_b  = (const float*)d_in[12];
  const float* bn3_g = (const float*)d_in[13];
  const float* bn3_b = (const float*)d_in[14];
  const float* fc1_w = (const float*)d_in[15];
  const float* fc1_b = (const float*)d_in[16];
  const float* fc2_w = (const float*)d_in[17];
  const float* fc2_b = (const float*)d_in[18];
  const float* fc3_w = (const float*)d_in[19];
  const float* fc3_b = (const float*)d_in[20];
  const float* fc4_w = (const float*)d_in[21];
  const float* fc4_b = (const float*)d_in[22];
  const float* ct1_w = (const float*)d_in[23];
  const float* ct1_b = (const float*)d_in[24];
  const float* bn4_g = (const float*)d_in[25];
  const float* bn4_b = (const float*)d_in[26];
  const float* ct2_w = (const float*)d_in[27];
  const float* ct2_b = (const float*)d_in[28];
  const float* bn5_g = (const float*)d_in[29];
  const float* bn5_b = (const float*)d_in[30];
  const float* ct3_w = (const float*)d_in[31];
  const float* ct3_b = (const float*)d_in[32];
  float* out = (float*)d_out;

  // ---- workspace layout (bytes; ~80 MB total, liveness-overlapped) ----
  char* ws = (char*)d_ws;
  unsigned char* zbuf = (unsigned char*)ws;             // 76,800
  float* x0   = (float*)(ws + 131072);                  // 76,800 B
  float* dm   = (float*)(ws + 262144);                  // SlotA fp32 23.0 MB
  float* ct3o = dm;                                     // SlotA reuse
  u16* c1o  = (u16*)(ws + 23306240);                    // SlotB 19.9 MB
  u16* ct2o = c1o;
  u16* c2o  = (u16*)(ws + 43233280);                    // SlotC 10.0 MB
  u16* ct1o = c2o;
  u16* c3o  = (u16*)(ws + 53198848);                    // SlotD 5.0 MB
  u16* f4   = c3o;
  u16* f1   = (u16*)(ws + 58183680);
  u16* f2   = (u16*)(ws + 58712064);
  u16* f3   = (u16*)(ws + 58781696);
  u16* wbA  = (u16*)(ws + 59310080);                    // fc1_w then fc4_w bf16
  u16* wb2  = (u16*)(ws + 79237120);
  u16* wb3  = (u16*)(ws + 79499264);

  // weight casts (fc4 cast happens after fc1 frees wbA)
  cast_kernel<<<9728, 256, 0, stream>>>(fc1_w, wbA, 2490368);
  cast_kernel<<<128, 256, 0, stream>>>(fc2_w, wb2, 32768);
  cast_kernel<<<128, 256, 0, stream>>>(fc3_w, wb3, 32768);

  prep_kernel<<<22500, 256, 0, stream>>>(x, dbn_g, dbn_b, dm, x0);
  zflag_kernel<<<300, 256, 0, stream>>>(dm, zbuf);

  // conv1: fp32 in (dm), bf16 out; 3->16, 299x25 -> 150x13
  conv_tiled_kernel<float, 3, 16, 16, 8, 299, 25, 150, 13, 30, 5>
      <<<dim3(5, 256), 256, 0, stream>>>(dm, c1_w, c1_b, bn1_g, bn1_b, c1o);
  // conv2: 16->32, 150x13 -> 75x7
  conv_tiled_kernel<u16, 16, 32, 32, 8, 150, 13, 75, 7, 19, 4>
      <<<dim3(4, 256), 256, 0, stream>>>(c1o, c2_w, c2_b, bn2_g, bn2_b, c2o);
  // conv3: 32->64, 75x7 -> 38x4
  conv_tiled_kernel<u16, 32, 64, 16, 8, 75, 7, 38, 4, 19, 2>
      <<<dim3(8, 256), 256, 0, stream>>>(c2o, c3_w, c3_b, bn3_g, bn3_b, c3o);

  fc_mfma_kernel<<<dim3(4, 16), 256, 0, stream>>>(c3o, wbA, fc1_b, f1, 9728, 1024);
  cast_kernel<<<9728, 256, 0, stream>>>(fc4_w, wbA, 2490368);
  fc_mfma_kernel<<<dim3(4, 2), 256, 0, stream>>>(f1, wb2, fc2_b, f2, 1024, 128);
  fc_mfma_kernel<<<dim3(4, 16), 256, 0, stream>>>(f2, wb3, fc3_b, f3, 128, 1024);
  fc_mfma_kernel<<<dim3(4, 152), 256, 0, stream>>>(f3, wbA, fc4_b, f4, 1024, 9728);

  // ct1: 64->32, (38,4)->(76,8)
  convt_tiled_kernel<64, 32, 16, 8, 38, 4, 76, 8, 38, 2>
      <<<dim3(4, 256), 256, 0, stream>>>(f4, ct1_w, ct1_b, bn4_g, bn4_b, ct1o);
  // ct2: 32->16, (76,8)->(152,16)
  convt_tiled_kernel<32, 16, 16, 8, 76, 8, 152, 16, 38, 4>
      <<<dim3(4, 256), 256, 0, stream>>>(ct1o, ct2_w, ct2_b, bn5_g, bn5_b, ct2o);
  // ct3: 16->3, (152,16)->(300,25) trimmed, tanh, fp32 out
  convt3_tiled_kernel<<<dim3(4, 256), 256, 0, stream>>>(ct2o, ct3_w, ct3_b, ct3o);

  scan_kernel<<<75, 256, 0, stream>>>(ct3o, x0, zbuf, out);
}

// Round 4
// 1182.417 us; speedup vs baseline: 4.3556x; 1.0796x over previous
//
#include <hip/hip_runtime.h>
#include <math.h>

#define LRELU(y) ((y) > 0.f ? (y) : 0.01f * (y))
__device__ __constant__ float BNS = 0.99999500003749969f; // 1/sqrt(1+1e-5)

typedef unsigned short u16;
typedef __attribute__((ext_vector_type(8))) short bf16x8;
typedef __attribute__((ext_vector_type(4))) float f32x4;

__device__ inline u16 f2b(float f) {
  union { float f; unsigned u; } x; x.f = f;
  return (u16)((x.u + 0x7FFFu + ((x.u >> 16) & 1u)) >> 16);
}
__device__ inline float b2f(u16 b) {
  union { unsigned u; float f; } x; x.u = ((unsigned)b) << 16;
  return x.f;
}
__device__ inline float ldv(const float* p) { return *p; }
__device__ inline float ldv(const u16* p) { return b2f(*p); }

// ---------------------------------------------------------------------------
// cast fp32 -> bf16, 4 elements/thread
// ---------------------------------------------------------------------------
__global__ __launch_bounds__(256) void cast_kernel(
    const float* __restrict__ s, u16* __restrict__ d, int n4) {
  int i = blockIdx.x * 256 + threadIdx.x;
  if (i >= n4) return;
  float4 v = ((const float4*)s)[i];
  ushort4 o;
  o.x = f2b(v.x); o.y = f2b(v.y); o.z = f2b(v.z); o.w = f2b(v.w);
  ((ushort4*)d)[i] = o;
}

// ---------------------------------------------------------------------------
// prep: x (128,3,300,25,2) -> dm (256,3,299,25) fp32, x0 (256,3,25) fp32
// ---------------------------------------------------------------------------
__global__ __launch_bounds__(256) void prep_kernel(
    const float* __restrict__ x, const float* __restrict__ g,
    const float* __restrict__ b, float* __restrict__ dm,
    float* __restrict__ x0) {
  int idx = blockIdx.x * 256 + threadIdx.x;  // (nm, c, t[0,300), v)
  if (idx >= 256 * 3 * 300 * 25) return;
  int v = idx % 25;
  int t = (idx / 25) % 300;
  int c = (idx / (25 * 300)) % 3;
  int nm = idx / (25 * 300 * 3);
  int n = nm >> 1, m = nm & 1;
  int ch = m * 75 + v * 3 + c;
  float s = g[ch] * BNS, bb = b[ch];
  long xi = (((long)(n * 3 + c) * 300 + t) * 25 + v) * 2 + m;
  float xm_t = x[xi] * s + bb;
  if (t == 0) x0[(nm * 3 + c) * 25 + v] = xm_t;
  if (t < 299) {
    float xm_t1 = x[xi + 50] * s + bb;
    dm[((nm * 3 + c) * 299 + t) * 25 + v] = xm_t1 - xm_t;
  }
}

// ---------------------------------------------------------------------------
// z flags: one wave per (nm,t); coalesced lane-parallel reads + ballot
// grid: 19200 blocks x 256 (4 waves/block)
// ---------------------------------------------------------------------------
__global__ __launch_bounds__(256) void zflag_kernel(
    const float* __restrict__ dm, unsigned char* __restrict__ z) {
  int gw = blockIdx.x * 4 + (threadIdx.x >> 6);
  if (gw >= 256 * 300) return;
  int lane = threadIdx.x & 63;
  int t = gw % 300, nm = gw / 300;
  bool nz = false;
  if (t < 299) {
    const float* base = dm + (long)nm * 3 * 299 * 25 + t * 25;
    if (lane < 75) {
      int c = lane / 25, v = lane % 25;
      nz = base[c * 299 * 25 + v] != 0.f;
    }
    int l2 = lane + 64;
    if (l2 < 75) {
      int c = l2 / 25, v = l2 % 25;
      nz = nz || (base[c * 299 * 25 + v] != 0.f);
    }
  }
  unsigned long long mask = __ballot(nz);
  if (lane == 0) z[nm * 300 + t] = (unsigned char)((t < 299) && (mask == 0ull));
}

// ---------------------------------------------------------------------------
// Tiled direct conv, stride 2, pad 1, 3x3. LDS input tile + weights.
// ---------------------------------------------------------------------------
template <typename TI, int IC, int OC, int OCB, int ACC, int H, int W, int OH,
          int OW, int TOH, int NTILE>
__global__ __launch_bounds__(256) void conv_tiled_kernel(
    const TI* __restrict__ in, const float* __restrict__ w,
    const float* __restrict__ cb, const float* __restrict__ bg,
    const float* __restrict__ bnb, u16* __restrict__ out) {
  constexpr int IHT = 2 * TOH + 1;
  constexpr int RL = W + 2;
  __shared__ float in_s[IC * IHT * RL];
  __shared__ float w_s[9 * IC * OCB];
  int bx = blockIdx.x;
  int nm = blockIdx.y;
  int tile = bx % NTILE;
  int oc0 = (bx / NTILE) * OCB;
  int oh0 = tile * TOH;
  int ih0 = 2 * oh0 - 1;
  const TI* inb = in + (long)nm * IC * H * W;
  for (int e = threadIdx.x; e < IC * IHT * RL; e += 256) {
    int c = e % RL;
    int r = (e / RL) % IHT;
    int ic = e / (RL * IHT);
    int ih = ih0 + r, iw = c - 1;
    float v = 0.f;
    if (ih >= 0 && ih < H && iw >= 0 && iw < W) v = ldv(&inb[(ic * H + ih) * W + iw]);
    in_s[e] = v;
  }
  for (int e = threadIdx.x; e < 9 * IC * OCB; e += 256) {
    int ocl = e % OCB;
    int ic = (e / OCB) % IC;
    int khw = e / (OCB * IC);
    int kh = khw / 3, kw = khw % 3;
    w_s[e] = w[(((oc0 + ocl) * IC + ic) * 3 + kh) * 3 + kw];
  }
  __syncthreads();
  constexpr int NPOS = TOH * OW;
  constexpr int NWI = NPOS * (OCB / ACC);
  for (int wi = threadIdx.x; wi < NWI; wi += 256) {
    int pos = wi % NPOS;
    int jb = (wi / NPOS) * ACC;
    int ow = pos % OW;
    int oh_l = pos / OW;
    int oh = oh0 + oh_l;
    if (oh >= OH) continue;
    float acc[ACC];
#pragma unroll
    for (int j = 0; j < ACC; ++j) acc[j] = 0.f;
    for (int kh = 0; kh < 3; ++kh) {
      int r = 2 * oh_l + kh;
      for (int kw = 0; kw < 3; ++kw) {
        int cc = 2 * ow + kw;
        const float* ip = &in_s[r * RL + cc];
        const float* wp = &w_s[(kh * 3 + kw) * IC * OCB + jb];
        for (int ic = 0; ic < IC; ++ic) {
          float a = ip[ic * IHT * RL];
#pragma unroll
          for (int j = 0; j < ACC; ++j) acc[j] += a * wp[ic * OCB + j];
        }
      }
    }
#pragma unroll
    for (int j = 0; j < ACC; ++j) {
      int oc = oc0 + jb + j;
      float y = (acc[j] + cb[oc]) * (bg[oc] * BNS) + bnb[oc];
      out[((long)nm * OC + oc) * OH * OW + oh * OW + ow] = f2b(LRELU(y));
    }
  }
}

// ---------------------------------------------------------------------------
// Tiled transposed conv (gather), stride 2, pad 1, 3x3. bf16 in/out.
// ---------------------------------------------------------------------------
template <int IC, int OC, int OCB, int ACC, int IH, int IW, int OH, int OW,
          int TOH, int NTILEH>
__global__ __launch_bounds__(256) void convt_tiled_kernel(
    const u16* __restrict__ in, const float* __restrict__ w,
    const float* __restrict__ cb, const float* __restrict__ bg,
    const float* __restrict__ bnb, u16* __restrict__ out) {
  constexpr int IHT = TOH / 2 + 1;
  constexpr int RL = IW + 1;
  __shared__ float in_s[IC * IHT * RL];
  __shared__ float w_s[9 * IC * OCB];
  int nm = blockIdx.y;
  int tile = blockIdx.x % NTILEH;
  int oc0 = (blockIdx.x / NTILEH) * OCB;
  int oh0 = tile * TOH;
  int ihb = oh0 / 2;
  const u16* inb = in + (long)nm * IC * IH * IW;
  for (int e = threadIdx.x; e < IC * IHT * RL; e += 256) {
    int c = e % RL;
    int r = (e / RL) % IHT;
    int ic = e / (RL * IHT);
    int ih = ihb + r;
    float v = 0.f;
    if (c < IW && ih < IH) v = ldv(&inb[(ic * IH + ih) * IW + c]);
    in_s[e] = v;
  }
  for (int e = threadIdx.x; e < 9 * IC * OCB; e += 256) {
    int ocl = e % OCB;
    int ic = (e / OCB) % IC;
    int khw = e / (OCB * IC);
    int kh = khw / 3, kw = khw % 3;
    w_s[e] = w[((ic * OC + oc0 + ocl) * 3 + kh) * 3 + kw];
  }
  __syncthreads();
  constexpr int NPOS = TOH * OW;
  constexpr int NWI = NPOS * (OCB / ACC);
  for (int wi = threadIdx.x; wi < NWI; wi += 256) {
    int pos = wi % NPOS;
    int jb = (wi / NPOS) * ACC;
    int ow = pos % OW;
    int oh = oh0 + pos / OW;
    float acc[ACC];
#pragma unroll
    for (int j = 0; j < ACC; ++j) acc[j] = 0.f;
    for (int kh = 0; kh < 3; ++kh) {
      int th = oh + 1 - kh;
      if (th & 1) continue;
      int r = (th >> 1) - ihb;
      for (int kw = 0; kw < 3; ++kw) {
        int tw = ow + 1 - kw;
        if (tw & 1) continue;
        int c = tw >> 1;
        const float* ip = &in_s[r * RL + c];
        const float* wp = &w_s[(kh * 3 + kw) * IC * OCB + jb];
        for (int ic = 0; ic < IC; ++ic) {
          float a = ip[ic * IHT * RL];
#pragma unroll
          for (int j = 0; j < ACC; ++j) acc[j] += a * wp[ic * OCB + j];
        }
      }
    }
#pragma unroll
    for (int j = 0; j < ACC; ++j) {
      int oc = oc0 + jb + j;
      float y = (acc[j] + cb[oc]) * (bg[oc] * BNS) + bnb[oc];
      out[((long)nm * OC + oc) * OH * OW + oh * OW + ow] = f2b(LRELU(y));
    }
  }
}

// ---------------------------------------------------------------------------
// convT3: 16->3, tanh fused, bf16 in, fp32 out trimmed to (256,3,300,25)
// ---------------------------------------------------------------------------
__global__ __launch_bounds__(256) void convt3_tiled_kernel(
    const u16* __restrict__ in, const float* __restrict__ w,
    const float* __restrict__ cb, float* __restrict__ out) {
  constexpr int IC = 16, IH = 152, IW = 16, TOH = 76, IHT = 39, RL = 17;
  __shared__ float in_s[IC * IHT * RL];
  __shared__ float w_s[9 * IC * 3];
  int nm = blockIdx.y;
  int oh0 = blockIdx.x * TOH;
  int ihb = oh0 / 2;
  const u16* inb = in + (long)nm * IC * IH * IW;
  for (int e = threadIdx.x; e < IC * IHT * RL; e += 256) {
    int c = e % RL;
    int r = (e / RL) % IHT;
    int ic = e / (RL * IHT);
    int ih = ihb + r;
    float v = 0.f;
    if (c < IW && ih < IH) v = ldv(&inb[(ic * IH + ih) * IW + c]);
    in_s[e] = v;
  }
  for (int e = threadIdx.x; e < 9 * IC * 3; e += 256) {
    int ocl = e % 3;
    int ic = (e / 3) % IC;
    int khw = e / (3 * IC);
    int kh = khw / 3, kw = khw % 3;
    w_s[e] = w[((ic * 3 + ocl) * 3 + kh) * 3 + kw];
  }
  __syncthreads();
  for (int wi = threadIdx.x; wi < TOH * 25; wi += 256) {
    int v = wi % 25;
    int t = oh0 + wi / 25;
    if (t >= 300) continue;
    float acc[3] = {0.f, 0.f, 0.f};
    for (int kh = 0; kh < 3; ++kh) {
      int th = t + 1 - kh;
      if (th & 1) continue;
      int r = (th >> 1) - ihb;
      for (int kw = 0; kw < 3; ++kw) {
        int tw = v + 1 - kw;
        if (tw & 1) continue;
        int c = tw >> 1;
        const float* ip = &in_s[r * RL + c];
        const float* wp = &w_s[(kh * 3 + kw) * IC * 3];
        for (int ic = 0; ic < IC; ++ic) {
          float a = ip[ic * IHT * RL];
#pragma unroll
          for (int j = 0; j < 3; ++j) acc[j] += a * wp[ic * 3 + j];
        }
      }
    }
#pragma unroll
    for (int j = 0; j < 3; ++j)
      out[((long)(nm * 3 + j) * 300 + t) * 25 + v] = tanhf(acc[j] + cb[j]);
  }
}

// ---------------------------------------------------------------------------
// FC via MFMA bf16, software-pipelined staging, optional split-K.
// A (256,K) bf16, Wt (N,K) bf16. Block: 64x64 tile, BK=64, 4 waves.
// grid (M/64, N/64, S). SPLIT: write fp32 partial[s][256][N];
// else fused bias+lrelu+bf16 out.
// ---------------------------------------------------------------------------
template <bool SPLIT>
__global__ __launch_bounds__(256) void fc_mfma_kernel(
    const u16* __restrict__ A, const u16* __restrict__ Wt,
    const float* __restrict__ bias, u16* __restrict__ out,
    float* __restrict__ partial, int K, int N, int ksegLen) {
  __shared__ u16 As[64][72];
  __shared__ u16 Bs[64][72];
  int tid = threadIdx.x;
  int m0 = blockIdx.x * 64, n0 = blockIdx.y * 64;
  long kbase = (long)blockIdx.z * ksegLen;
  int row = tid >> 3;          // 0..31 (handles row and row+32)
  int seg = (tid & 7) * 8;
  const u16* ap0 = A + (long)(m0 + row) * K + kbase + seg;
  const u16* ap1 = A + (long)(m0 + row + 32) * K + kbase + seg;
  const u16* bp0 = Wt + (long)(n0 + row) * K + kbase + seg;
  const u16* bp1 = Wt + (long)(n0 + row + 32) * K + kbase + seg;
  uint4 ra0 = *(const uint4*)ap0;
  uint4 ra1 = *(const uint4*)ap1;
  uint4 rb0 = *(const uint4*)bp0;
  uint4 rb1 = *(const uint4*)bp1;
  int wv = tid >> 6, lane = tid & 63;
  int lr = lane & 15, q = lane >> 4;
  int mb = (wv >> 1) * 32, nb = (wv & 1) * 32;
  f32x4 acc[2][2] = {};
  for (int k0 = 0; k0 < ksegLen; k0 += 64) {
    *(uint4*)&As[row][seg] = ra0;
    *(uint4*)&As[row + 32][seg] = ra1;
    *(uint4*)&Bs[row][seg] = rb0;
    *(uint4*)&Bs[row + 32][seg] = rb1;
    __syncthreads();
    if (k0 + 64 < ksegLen) {
      ra0 = *(const uint4*)(ap0 + k0 + 64);
      ra1 = *(const uint4*)(ap1 + k0 + 64);
      rb0 = *(const uint4*)(bp0 + k0 + 64);
      rb1 = *(const uint4*)(bp1 + k0 + 64);
    }
#pragma unroll
    for (int kk = 0; kk < 64; kk += 32) {
      bf16x8 a0 = *(bf16x8*)&As[mb + lr][kk + q * 8];
      bf16x8 a1 = *(bf16x8*)&As[mb + 16 + lr][kk + q * 8];
      bf16x8 b0 = *(bf16x8*)&Bs[nb + lr][kk + q * 8];
      bf16x8 b1 = *(bf16x8*)&Bs[nb + 16 + lr][kk + q * 8];
      acc[0][0] = __builtin_amdgcn_mfma_f32_16x16x32_bf16(a0, b0, acc[0][0], 0, 0, 0);
      acc[0][1] = __builtin_amdgcn_mfma_f32_16x16x32_bf16(a0, b1, acc[0][1], 0, 0, 0);
      acc[1][0] = __builtin_amdgcn_mfma_f32_16x16x32_bf16(a1, b0, acc[1][0], 0, 0, 0);
      acc[1][1] = __builtin_amdgcn_mfma_f32_16x16x32_bf16(a1, b1, acc[1][1], 0, 0, 0);
    }
    __syncthreads();
  }
#pragma unroll
  for (int mi = 0; mi < 2; ++mi)
#pragma unroll
    for (int ni = 0; ni < 2; ++ni) {
      int col = n0 + nb + ni * 16 + lr;
      float bv = SPLIT ? 0.f : bias[col];
#pragma unroll
      for (int r = 0; r < 4; ++r) {
        int grow = m0 + mb + mi * 16 + q * 4 + r;
        float y = acc[mi][ni][r];
        if (SPLIT) {
          partial[((long)blockIdx.z * 256 + grow) * N + col] = y;
        } else {
          out[(long)grow * N + col] = f2b(LRELU(y + bv));
        }
      }
    }
}

// ---------------------------------------------------------------------------
// split-K reduce: sum S partials, + bias, lrelu, cast bf16. 4 elems/thread.
// ---------------------------------------------------------------------------
__global__ __launch_bounds__(256) void fc_reduce_kernel(
    const float* __restrict__ partial, const float* __restrict__ bias,
    u16* __restrict__ out, int MN, int N, int S) {
  int i = blockIdx.x * 256 + threadIdx.x;
  if (i * 4 >= MN) return;
  float4 s = ((const float4*)partial)[i];
  for (int t = 1; t < S; ++t) {
    float4 p = ((const float4*)partial)[(long)t * (MN >> 2) + i];
    s.x += p.x; s.y += p.y; s.z += p.z; s.w += p.w;
  }
  int col = (i * 4) % N;
  float4 bv = *(const float4*)(bias + col);
  ushort4 o;
  o.x = f2b(LRELU(s.x + bv.x));
  o.y = f2b(LRELU(s.y + bv.y));
  o.z = f2b(LRELU(s.z + bv.z));
  o.w = f2b(LRELU(s.w + bv.w));
  ((ushort4*)out)[i] = o;
}

// ---------------------------------------------------------------------------
// segmented scan over t
// ---------------------------------------------------------------------------
__global__ __launch_bounds__(256) void scan_kernel(
    const float* __restrict__ dec, const float* __restrict__ x0,
    const unsigned char* __restrict__ z, float* __restrict__ out) {
  int idx = blockIdx.x * 256 + threadIdx.x;  // (nm, c, v)
  if (idx >= 256 * 75) return;
  int v = idx % 25;
  int c = (idx / 25) % 3;
  int nm = idx / 75;
  int n = nm >> 1, m = nm & 1;
  const float* db = dec + ((long)(nm * 3 + c) * 300) * 25 + v;
  const unsigned char* zb = z + nm * 300;
  float* ob = out + (((long)(n * 3 + c) * 300) * 25 + v) * 2 + m;
  float x0v = x0[(nm * 3 + c) * 25 + v];
  float carry = 0.f;
  for (int t0 = 0; t0 < 300; t0 += 10) {
    float vals[10];
#pragma unroll
    for (int i = 0; i < 10; ++i) vals[i] = db[(t0 + i) * 25];
#pragma unroll
    for (int i = 0; i < 10; ++i) {
      int t = t0 + i;
      float d = (t == 0) ? x0v : vals[i];
      carry = zb[t] ? 0.f : (d + carry);
      ob[(long)t * 50] = carry;
    }
  }
}

// ---------------------------------------------------------------------------
extern "C" void kernel_launch(void* const* d_in, const int* in_sizes, int n_in,
                              void* d_out, int out_size, void* d_ws, size_t ws_size,
                              hipStream_t stream) {
  const float* x     = (const float*)d_in[0];
  const float* dbn_g = (const float*)d_in[1];
  const float* dbn_b = (const float*)d_in[2];
  const float* c1_w  = (const float*)d_in[3];
  const float* c1_b  = (const float*)d_in[4];
  const float* bn1_g = (const float*)d_in[5];
  const float* bn1_b = (const float*)d_in[6];
  const float* c2_w  = (const float*)d_in[7];
  const float* c2_b  = (const float*)d_in[8];
  const float* bn2_g = (const float*)d_in[9];
  const float* bn2_b = (const float*)d_in[10];
  const float* c3_w  = (const float*)d_in[11];
  const float* c3_b  = (const float*)d_in[12];
  const float* bn3_g = (const float*)d_in[13];
  const float* bn3_b = (const float*)d_in[14];
  const float* fc1_w = (const float*)d_in[15];
  const float* fc1_b = (const float*)d_in[16];
  const float* fc2_w = (const float*)d_in[17];
  const float* fc2_b = (const float*)d_in[18];
  const float* fc3_w = (const float*)d_in[19];
  const float* fc3_b = (const float*)d_in[20];
  const float* fc4_w = (const float*)d_in[21];
  const float* fc4_b = (const float*)d_in[22];
  const float* ct1_w = (const float*)d_in[23];
  const float* ct1_b = (const float*)d_in[24];
  const float* bn4_g = (const float*)d_in[25];
  const float* bn4_b = (const float*)d_in[26];
  const float* ct2_w = (const float*)d_in[27];
  const float* ct2_b = (const float*)d_in[28];
  const float* bn5_g = (const float*)d_in[29];
  const float* bn5_b = (const float*)d_in[30];
  const float* ct3_w = (const float*)d_in[31];
  const float* ct3_b = (const float*)d_in[32];
  float* out = (float*)d_out;

  // ---- workspace layout (bytes; ~88 MB, liveness-overlapped) ----
  char* ws = (char*)d_ws;
  unsigned char* zbuf = (unsigned char*)ws;             // 76,800
  float* x0   = (float*)(ws + 131072);
  float* dm   = (float*)(ws + 262144);                  // SlotA fp32 23 MB
  float* ct3o = dm;
  u16* c1o  = (u16*)(ws + 23306240);                    // SlotB
  u16* ct2o = c1o;
  u16* c2o  = (u16*)(ws + 43233280);                    // SlotC
  u16* ct1o = c2o;
  u16* c3o  = (u16*)(ws + 53198848);                    // SlotD
  u16* f4   = c3o;
  u16* f1   = (u16*)(ws + 58183680);
  u16* f2   = (u16*)(ws + 58712064);
  u16* f3   = (u16*)(ws + 58781696);
  u16* wbA  = (u16*)(ws + 59310080);                    // fc1_w then fc4_w bf16
  u16* wb2  = (u16*)(ws + 79237120);
  u16* wb3  = (u16*)(ws + 79499264);
  float* partial = (float*)(ws + 79761408);             // 8 MB split-K partials

  cast_kernel<<<9728, 256, 0, stream>>>(fc1_w, wbA, 2490368);
  cast_kernel<<<128, 256, 0, stream>>>(fc2_w, wb2, 32768);
  cast_kernel<<<128, 256, 0, stream>>>(fc3_w, wb3, 32768);

  prep_kernel<<<22500, 256, 0, stream>>>(x, dbn_g, dbn_b, dm, x0);
  zflag_kernel<<<19200, 256, 0, stream>>>(dm, zbuf);

  conv_tiled_kernel<float, 3, 16, 16, 8, 299, 25, 150, 13, 30, 5>
      <<<dim3(5, 256), 256, 0, stream>>>(dm, c1_w, c1_b, bn1_g, bn1_b, c1o);
  conv_tiled_kernel<u16, 16, 32, 32, 8, 150, 13, 75, 7, 19, 4>
      <<<dim3(4, 256), 256, 0, stream>>>(c1o, c2_w, c2_b, bn2_g, bn2_b, c2o);
  conv_tiled_kernel<u16, 32, 64, 16, 8, 75, 7, 38, 4, 19, 2>
      <<<dim3(8, 256), 256, 0, stream>>>(c2o, c3_w, c3_b, bn3_g, bn3_b, c3o);

  // fc1: split-K=8 (9728 = 8*1216)
  fc_mfma_kernel<true><<<dim3(4, 16, 8), 256, 0, stream>>>(
      c3o, wbA, nullptr, nullptr, partial, 9728, 1024, 1216);
  fc_reduce_kernel<<<256, 256, 0, stream>>>(partial, fc1_b, f1, 262144, 1024, 8);
  cast_kernel<<<9728, 256, 0, stream>>>(fc4_w, wbA, 2490368);
  // fc2: split-K=16 (1024 = 16*64)
  fc_mfma_kernel<true><<<dim3(4, 2, 16), 256, 0, stream>>>(
      f1, wb2, nullptr, nullptr, partial, 1024, 128, 64);
  fc_reduce_kernel<<<32, 256, 0, stream>>>(partial, fc2_b, f2, 32768, 128, 16);
  // fc3: split-K=2 (128 = 2*64)
  fc_mfma_kernel<true><<<dim3(4, 16, 2), 256, 0, stream>>>(
      f2, wb3, nullptr, nullptr, partial, 128, 1024, 64);
  fc_reduce_kernel<<<256, 256, 0, stream>>>(partial, fc3_b, f3, 262144, 1024, 2);
  // fc4: direct (608 blocks)
  fc_mfma_kernel<false><<<dim3(4, 152, 1), 256, 0, stream>>>(
      f3, wbA, fc4_b, f4, nullptr, 1024, 9728, 1024);

  convt_tiled_kernel<64, 32, 16, 8, 38, 4, 76, 8, 38, 2>
      <<<dim3(4, 256), 256, 0, stream>>>(f4, ct1_w, ct1_b, bn4_g, bn4_b, ct1o);
  convt_tiled_kernel<32, 16, 16, 8, 76, 8, 152, 16, 38, 4>
      <<<dim3(4, 256), 256, 0, stream>>>(ct1o, ct2_w, ct2_b, bn5_g, bn5_b, ct2o);
  convt3_tiled_kernel<<<dim3(4, 256), 256, 0, stream>>>(ct2o, ct3_w, ct3_b, ct3o);

  scan_kernel<<<75, 256, 0, stream>>>(ct3o, x0, zbuf, out);
}

// Round 5
// 886.711 us; speedup vs baseline: 5.8082x; 1.3335x over previous
//
#include <hip/hip_runtime.h>
#include <math.h>

#define LRELU(y) ((y) > 0.f ? (y) : 0.01f * (y))
__device__ __constant__ float BNS = 0.99999500003749969f; // 1/sqrt(1+1e-5)

typedef unsigned short u16;
typedef __attribute__((ext_vector_type(8))) short bf16x8;
typedef __attribute__((ext_vector_type(4))) float f32x4;

__device__ inline u16 f2b(float f) {
  union { float f; unsigned u; } x; x.f = f;
  return (u16)((x.u + 0x7FFFu + ((x.u >> 16) & 1u)) >> 16);
}
__device__ inline float b2f(u16 b) {
  union { unsigned u; float f; } x; x.u = ((unsigned)b) << 16;
  return x.f;
}
__device__ inline float ldv(const float* p) { return *p; }
__device__ inline float ldv(const u16* p) { return b2f(*p); }

__device__ inline void fma16(float (&acc)[4][4], float4 iv, float4 wv) {
  acc[0][0] += iv.x * wv.x; acc[0][1] += iv.x * wv.y;
  acc[0][2] += iv.x * wv.z; acc[0][3] += iv.x * wv.w;
  acc[1][0] += iv.y * wv.x; acc[1][1] += iv.y * wv.y;
  acc[1][2] += iv.y * wv.z; acc[1][3] += iv.y * wv.w;
  acc[2][0] += iv.z * wv.x; acc[2][1] += iv.z * wv.y;
  acc[2][2] += iv.z * wv.z; acc[2][3] += iv.z * wv.w;
  acc[3][0] += iv.w * wv.x; acc[3][1] += iv.w * wv.y;
  acc[3][2] += iv.w * wv.z; acc[3][3] += iv.w * wv.w;
}

// ---------------------------------------------------------------------------
// cast fp32 -> bf16
// ---------------------------------------------------------------------------
__global__ __launch_bounds__(256) void cast_kernel(
    const float* __restrict__ s, u16* __restrict__ d, int n4) {
  int i = blockIdx.x * 256 + threadIdx.x;
  if (i >= n4) return;
  float4 v = ((const float4*)s)[i];
  ushort4 o;
  o.x = f2b(v.x); o.y = f2b(v.y); o.z = f2b(v.z); o.w = f2b(v.w);
  ((ushort4*)d)[i] = o;
}

// fc1 weight: cast + permute columns k=oc*152+sp -> k'=sp*64+oc
__global__ __launch_bounds__(256) void wcast_fc1_kernel(
    const float* __restrict__ w, u16* __restrict__ wp) {
  int idx = blockIdx.x * 256 + threadIdx.x;
  if (idx >= 1024 * 9728) return;
  int n = idx / 9728, kp = idx % 9728;
  int sp = kp >> 6, oc = kp & 63;
  wp[idx] = f2b(w[(long)n * 9728 + oc * 152 + sp]);
}

// conv weight -> padded bf16 (64 x KP), zero pad rows>=OC, cols>=K
__global__ __launch_bounds__(256) void wpad_kernel(
    const float* __restrict__ w, u16* __restrict__ wp, int OC, int K, int KP) {
  int idx = blockIdx.x * 256 + threadIdx.x;
  if (idx >= 64 * KP) return;
  int row = idx / KP, col = idx % KP;
  wp[idx] = (row < OC && col < K) ? f2b(w[row * K + col]) : (u16)0;
}

// ---------------------------------------------------------------------------
// prep: x (128,3,300,25,2) -> dm (256,3,299,25) fp32, x0 (256,3,25) fp32
// ---------------------------------------------------------------------------
__global__ __launch_bounds__(256) void prep_kernel(
    const float* __restrict__ x, const float* __restrict__ g,
    const float* __restrict__ b, float* __restrict__ dm,
    float* __restrict__ x0) {
  int idx = blockIdx.x * 256 + threadIdx.x;
  if (idx >= 256 * 3 * 300 * 25) return;
  int v = idx % 25;
  int t = (idx / 25) % 300;
  int c = (idx / (25 * 300)) % 3;
  int nm = idx / (25 * 300 * 3);
  int n = nm >> 1, m = nm & 1;
  int ch = m * 75 + v * 3 + c;
  float s = g[ch] * BNS, bb = b[ch];
  long xi = (((long)(n * 3 + c) * 300 + t) * 25 + v) * 2 + m;
  float xm_t = x[xi] * s + bb;
  if (t == 0) x0[(nm * 3 + c) * 25 + v] = xm_t;
  if (t < 299) {
    float xm_t1 = x[xi + 50] * s + bb;
    dm[((nm * 3 + c) * 299 + t) * 25 + v] = xm_t1 - xm_t;
  }
}

// ---------------------------------------------------------------------------
// z flags: one wave per (nm,t)
// ---------------------------------------------------------------------------
__global__ __launch_bounds__(256) void zflag_kernel(
    const float* __restrict__ dm, unsigned char* __restrict__ z) {
  int gw = blockIdx.x * 4 + (threadIdx.x >> 6);
  if (gw >= 256 * 300) return;
  int lane = threadIdx.x & 63;
  int t = gw % 300, nm = gw / 300;
  bool nz = false;
  if (t < 299) {
    const float* base = dm + (long)nm * 3 * 299 * 25 + t * 25;
    if (lane < 75) {
      int c = lane / 25, v = lane % 25;
      nz = base[c * 299 * 25 + v] != 0.f;
    }
    int l2 = lane + 64;
    if (l2 < 75) {
      int c = l2 / 25, v = l2 % 25;
      nz = nz || (base[c * 299 * 25 + v] != 0.f);
    }
  }
  unsigned long long mask = __ballot(nz);
  if (lane == 0) z[nm * 300 + t] = (unsigned char)((t < 299) && (mask == 0ull));
}

// ---------------------------------------------------------------------------
// conv1 (VALU tiled, fp32 in, bf16 out) — kept from R4
// ---------------------------------------------------------------------------
template <typename TI, int IC, int OC, int OCB, int ACC, int H, int W, int OH,
          int OW, int TOH, int NTILE>
__global__ __launch_bounds__(256) void conv_tiled_kernel(
    const TI* __restrict__ in, const float* __restrict__ w,
    const float* __restrict__ cb, const float* __restrict__ bg,
    const float* __restrict__ bnb, u16* __restrict__ out) {
  constexpr int IHT = 2 * TOH + 1;
  constexpr int RL = W + 2;
  __shared__ float in_s[IC * IHT * RL];
  __shared__ float w_s[9 * IC * OCB];
  int bx = blockIdx.x;
  int nm = blockIdx.y;
  int tile = bx % NTILE;
  int oc0 = (bx / NTILE) * OCB;
  int oh0 = tile * TOH;
  int ih0 = 2 * oh0 - 1;
  const TI* inb = in + (long)nm * IC * H * W;
  for (int e = threadIdx.x; e < IC * IHT * RL; e += 256) {
    int c = e % RL;
    int r = (e / RL) % IHT;
    int ic = e / (RL * IHT);
    int ih = ih0 + r, iw = c - 1;
    float v = 0.f;
    if (ih >= 0 && ih < H && iw >= 0 && iw < W) v = ldv(&inb[(ic * H + ih) * W + iw]);
    in_s[e] = v;
  }
  for (int e = threadIdx.x; e < 9 * IC * OCB; e += 256) {
    int ocl = e % OCB;
    int ic = (e / OCB) % IC;
    int khw = e / (OCB * IC);
    int kh = khw / 3, kw = khw % 3;
    w_s[e] = w[(((oc0 + ocl) * IC + ic) * 3 + kh) * 3 + kw];
  }
  __syncthreads();
  constexpr int NPOS = TOH * OW;
  constexpr int NWI = NPOS * (OCB / ACC);
  for (int wi = threadIdx.x; wi < NWI; wi += 256) {
    int pos = wi % NPOS;
    int jb = (wi / NPOS) * ACC;
    int ow = pos % OW;
    int oh_l = pos / OW;
    int oh = oh0 + oh_l;
    if (oh >= OH) continue;
    float acc[ACC];
#pragma unroll
    for (int j = 0; j < ACC; ++j) acc[j] = 0.f;
    for (int kh = 0; kh < 3; ++kh) {
      int r = 2 * oh_l + kh;
      for (int kw = 0; kw < 3; ++kw) {
        int cc = 2 * ow + kw;
        const float* ip = &in_s[r * RL + cc];
        const float* wp = &w_s[(kh * 3 + kw) * IC * OCB + jb];
        for (int ic = 0; ic < IC; ++ic) {
          float a = ip[ic * IHT * RL];
#pragma unroll
          for (int j = 0; j < ACC; ++j) acc[j] += a * wp[ic * OCB + j];
        }
      }
    }
#pragma unroll
    for (int j = 0; j < ACC; ++j) {
      int oc = oc0 + jb + j;
      float y = (acc[j] + cb[oc]) * (bg[oc] * BNS) + bnb[oc];
      out[((long)nm * OC + oc) * OH * OW + oh * OW + ow] = f2b(LRELU(y));
    }
  }
}

// ---------------------------------------------------------------------------
// im2col: build bf16 patch (m, KP) from NCHW or NHWC bf16 input, stride-2,
// pad 1, 3x3. k-order = ic*9 + kh*3 + kw (matches w row-major flatten).
// ---------------------------------------------------------------------------
template <int IC, int H, int W, int OWW, int K, int KP, bool NHWC>
__global__ __launch_bounds__(256) void im2col_kernel(
    const u16* __restrict__ in, u16* __restrict__ patch, int m_off,
    int spatial, int n_threads) {
  int idx = blockIdx.x * 256 + threadIdx.x;
  if (idx >= n_threads) return;
  constexpr int KP8 = KP / 8;
  int m = idx / KP8;
  int k0 = (idx % KP8) * 8;
  int gm = m_off + m;
  int nm = gm / spatial, sp = gm % spatial;
  int oh = sp / OWW, ow = sp % OWW;
  __align__(16) u16 vals[8];
#pragma unroll
  for (int j = 0; j < 8; ++j) {
    int k = k0 + j;
    u16 v = 0;
    if (k < K) {
      int ic = k / 9, tap = k % 9;
      int ih = 2 * oh + tap / 3 - 1, iw = 2 * ow + tap % 3 - 1;
      if ((unsigned)ih < (unsigned)H && (unsigned)iw < (unsigned)W)
        v = NHWC ? in[((long)nm * H * W + ih * W + iw) * IC + ic]
                 : in[((long)nm * IC + ic) * H * W + ih * W + iw];
    }
    vals[j] = v;
  }
  *(uint4*)(patch + (long)m * KP + k0) = *(uint4*)vals;
}

// ---------------------------------------------------------------------------
// MFMA GEMM: out[m][n] = epilogue(sum_k A[m][k]*Wt[n][k]).
// EPI: 0=split-K fp32 partial; 1=bias+lrelu bf16; 2=conv BN+lrelu bf16
//      (p0=conv bias, p1=bn gamma, p2=bn beta, col guard col<nvalid)
// ---------------------------------------------------------------------------
template <int EPI>
__global__ __launch_bounds__(256) void fc_mfma_kernel(
    const u16* __restrict__ A, const u16* __restrict__ Wt,
    const float* __restrict__ p0, const float* __restrict__ p1,
    const float* __restrict__ p2, u16* __restrict__ out,
    float* __restrict__ partial, int K, int N, int ksegLen, int nvalid) {
  __shared__ u16 As[64][72];
  __shared__ u16 Bs[64][72];
  int tid = threadIdx.x;
  int m0 = blockIdx.x * 64, n0 = blockIdx.y * 64;
  long kbase = (long)blockIdx.z * ksegLen;
  int row = tid >> 3;
  int seg = (tid & 7) * 8;
  const u16* ap0 = A + (long)(m0 + row) * K + kbase + seg;
  const u16* ap1 = A + (long)(m0 + row + 32) * K + kbase + seg;
  const u16* bp0 = Wt + (long)(n0 + row) * K + kbase + seg;
  const u16* bp1 = Wt + (long)(n0 + row + 32) * K + kbase + seg;
  uint4 ra0 = *(const uint4*)ap0;
  uint4 ra1 = *(const uint4*)ap1;
  uint4 rb0 = *(const uint4*)bp0;
  uint4 rb1 = *(const uint4*)bp1;
  int wv = tid >> 6, lane = tid & 63;
  int lr = lane & 15, q = lane >> 4;
  int mb = (wv >> 1) * 32, nb = (wv & 1) * 32;
  f32x4 acc[2][2] = {};
  for (int k0 = 0; k0 < ksegLen; k0 += 64) {
    *(uint4*)&As[row][seg] = ra0;
    *(uint4*)&As[row + 32][seg] = ra1;
    *(uint4*)&Bs[row][seg] = rb0;
    *(uint4*)&Bs[row + 32][seg] = rb1;
    __syncthreads();
    if (k0 + 64 < ksegLen) {
      ra0 = *(const uint4*)(ap0 + k0 + 64);
      ra1 = *(const uint4*)(ap1 + k0 + 64);
      rb0 = *(const uint4*)(bp0 + k0 + 64);
      rb1 = *(const uint4*)(bp1 + k0 + 64);
    }
#pragma unroll
    for (int kk = 0; kk < 64; kk += 32) {
      bf16x8 a0 = *(bf16x8*)&As[mb + lr][kk + q * 8];
      bf16x8 a1 = *(bf16x8*)&As[mb + 16 + lr][kk + q * 8];
      bf16x8 b0 = *(bf16x8*)&Bs[nb + lr][kk + q * 8];
      bf16x8 b1 = *(bf16x8*)&Bs[nb + 16 + lr][kk + q * 8];
      acc[0][0] = __builtin_amdgcn_mfma_f32_16x16x32_bf16(a0, b0, acc[0][0], 0, 0, 0);
      acc[0][1] = __builtin_amdgcn_mfma_f32_16x16x32_bf16(a0, b1, acc[0][1], 0, 0, 0);
      acc[1][0] = __builtin_amdgcn_mfma_f32_16x16x32_bf16(a1, b0, acc[1][0], 0, 0, 0);
      acc[1][1] = __builtin_amdgcn_mfma_f32_16x16x32_bf16(a1, b1, acc[1][1], 0, 0, 0);
    }
    __syncthreads();
  }
#pragma unroll
  for (int mi = 0; mi < 2; ++mi)
#pragma unroll
    for (int ni = 0; ni < 2; ++ni) {
      int col = n0 + nb + ni * 16 + lr;
      if (EPI == 2 && col >= nvalid) continue;
      float b0v = 0.f, scv = 1.f, shv = 0.f;
      if (EPI == 1) b0v = p0[col];
      if (EPI == 2) { b0v = p0[col]; scv = p1[col] * BNS; shv = p2[col]; }
#pragma unroll
      for (int r = 0; r < 4; ++r) {
        int grow = m0 + mb + mi * 16 + q * 4 + r;
        float y = acc[mi][ni][r];
        if (EPI == 0) {
          partial[((long)blockIdx.z * 256 + grow) * N + col] = y;
        } else if (EPI == 1) {
          out[(long)grow * N + col] = f2b(LRELU(y + b0v));
        } else {
          out[(long)grow * N + col] = f2b(LRELU((y + b0v) * scv + shv));
        }
      }
    }
}

// ---------------------------------------------------------------------------
// split-K reduce
// ---------------------------------------------------------------------------
__global__ __launch_bounds__(256) void fc_reduce_kernel(
    const float* __restrict__ partial, const float* __restrict__ bias,
    u16* __restrict__ out, int MN, int N, int S) {
  int i = blockIdx.x * 256 + threadIdx.x;
  if (i * 4 >= MN) return;
  float4 s = ((const float4*)partial)[i];
  for (int t = 1; t < S; ++t) {
    float4 p = ((const float4*)partial)[(long)t * (MN >> 2) + i];
    s.x += p.x; s.y += p.y; s.z += p.z; s.w += p.w;
  }
  int col = (i * 4) % N;
  float4 bv = *(const float4*)(bias + col);
  ushort4 o;
  o.x = f2b(LRELU(s.x + bv.x));
  o.y = f2b(LRELU(s.y + bv.y));
  o.z = f2b(LRELU(s.z + bv.z));
  o.w = f2b(LRELU(s.w + bv.w));
  ((ushort4*)out)[i] = o;
}

// ---------------------------------------------------------------------------
// Transposed conv via parity classes. 4x4 (spatial x oc) register tile,
// float4 LDS reads. bf16 NCHW in/out, fused BN+lrelu.
// grid: (NTILEH * OCTOT/OCB, 256)
// ---------------------------------------------------------------------------
template <int IC, int OCTOT, int OCB, int IH, int IW, int TOH, int NTILEH>
__global__ __launch_bounds__(256) void convt_cls_kernel(
    const u16* __restrict__ in, const float* __restrict__ w,
    const float* __restrict__ cb, const float* __restrict__ bg,
    const float* __restrict__ bnb, u16* __restrict__ out) {
  constexpr int AA = TOH / 2;
  constexpr int IHT = AA + 1;
  constexpr int RW = IW + 4;
  constexpr int OH = 2 * IH, OW = 2 * IW;
  constexpr int BG = IW / 4;
  constexpr int OG = OCB / 4;
  constexpr int CLS = AA * BG * OG;
  __shared__ float in_s[IC * IHT * RW];
  __shared__ float w_s[9 * IC * OCB];
  int nm = blockIdx.y;
  int tile = blockIdx.x % NTILEH;
  int oc0 = (blockIdx.x / NTILEH) * OCB;
  int oh0 = tile * TOH;
  int ihb = oh0 >> 1;
  const u16* inb = in + (long)nm * IC * IH * IW;
  for (int e = threadIdx.x; e < IC * IHT * RW; e += 256) {
    int cw = e % RW;
    int r = (e / RW) % IHT;
    int ic = e / (RW * IHT);
    int ih = ihb + r;
    float v = 0.f;
    if (cw < IW && ih < IH) v = b2f(inb[(ic * IH + ih) * IW + cw]);
    in_s[e] = v;
  }
  for (int e = threadIdx.x; e < 9 * IC * OCB; e += 256) {
    int ocl = e % OCB;
    int ic = (e / OCB) % IC;
    int khw = e / (OCB * IC);
    w_s[e] = w[(ic * OCTOT + oc0 + ocl) * 9 + khw];
  }
  __syncthreads();
  for (int wi = threadIdx.x; wi < 4 * CLS; wi += 256) {
    int cls = wi / CLS;
    int rem = wi % CLS;
    int a = rem % AA; rem /= AA;
    int bgi = rem % BG;
    int og = rem / BG;
    int p = cls >> 1, q = cls & 1;
    int b0 = bgi * 4, oc = og * 4;
    float acc[4][4] = {};
    for (int kh = 0; kh < 3; ++kh) {
      int th = p + 1 - kh;
      if (th & 1) continue;
      int r = a + (th >> 1);
      const float* ib = &in_s[r * RW + b0];
      const float* wb = &w_s[(kh * 3) * IC * OCB + oc];
      for (int ic = 0; ic < IC; ++ic) {
        float4 iv0 = *(const float4*)(ib + ic * IHT * RW);
        if (q == 0) {
          float4 wv = *(const float4*)(wb + (IC + ic) * OCB);  // kw=1
          fma16(acc, iv0, wv);
        } else {
          float4 iv4 = *(const float4*)(ib + ic * IHT * RW + 4);
          float4 wv2 = *(const float4*)(wb + (2 * IC + ic) * OCB);  // kw=2
          fma16(acc, iv0, wv2);
          float4 sh;
          sh.x = iv0.y; sh.y = iv0.z; sh.z = iv0.w; sh.w = iv4.x;
          float4 wv0 = *(const float4*)(wb + ic * OCB);  // kw=0
          fma16(acc, sh, wv0);
        }
      }
    }
    int oh = oh0 + 2 * a + p;
    if (oh >= OH) continue;
    float cc[4], ss[4], hh[4];
#pragma unroll
    for (int j = 0; j < 4; ++j) {
      int o = oc0 + oc + j;
      cc[j] = cb[o]; ss[j] = bg[o] * BNS; hh[j] = bnb[o];
    }
#pragma unroll
    for (int b = 0; b < 4; ++b) {
      int ow = 2 * (b0 + b) + q;
#pragma unroll
      for (int j = 0; j < 4; ++j) {
        float y = (acc[b][j] + cc[j]) * ss[j] + hh[j];
        out[((long)(nm * OCTOT + oc0 + oc + j) * OH + oh) * OW + ow] =
            f2b(LRELU(y));
      }
    }
  }
}

// ---------------------------------------------------------------------------
// ct3 parity-class: 16->3 (padded to 4), tanh, fp32 out trimmed (256,3,300,25)
// grid (4, 256)
// ---------------------------------------------------------------------------
__global__ __launch_bounds__(256) void convt3_cls_kernel(
    const u16* __restrict__ in, const float* __restrict__ w,
    const float* __restrict__ cb, float* __restrict__ out) {
  constexpr int IC = 16, IH = 152, IW = 16, TOH = 76;
  constexpr int AA = 38, IHT = 39, RW = 20, BG = 4, CLS = AA * BG;
  __shared__ float in_s[IC * IHT * RW];
  __shared__ float w_s[9 * IC * 4];
  int nm = blockIdx.y;
  int oh0 = blockIdx.x * TOH;
  int ihb = oh0 >> 1;
  const u16* inb = in + (long)nm * IC * IH * IW;
  for (int e = threadIdx.x; e < IC * IHT * RW; e += 256) {
    int cw = e % RW;
    int r = (e / RW) % IHT;
    int ic = e / (RW * IHT);
    int ih = ihb + r;
    float v = 0.f;
    if (cw < IW && ih < IH) v = b2f(inb[(ic * IH + ih) * IW + cw]);
    in_s[e] = v;
  }
  for (int e = threadIdx.x; e < 9 * IC * 4; e += 256) {
    int ocl = e % 4;
    int ic = (e / 4) % IC;
    int khw = e / 64;
    w_s[e] = (ocl < 3) ? w[(ic * 3 + ocl) * 9 + khw] : 0.f;
  }
  __syncthreads();
  float c3[3] = {cb[0], cb[1], cb[2]};
  for (int wi = threadIdx.x; wi < 4 * CLS; wi += 256) {
    int cls = wi / CLS;
    int rem = wi % CLS;
    int a = rem % AA;
    int bgi = rem / AA;
    int p = cls >> 1, q = cls & 1;
    int b0 = bgi * 4;
    float acc[4][4] = {};
    for (int kh = 0; kh < 3; ++kh) {
      int th = p + 1 - kh;
      if (th & 1) continue;
      int r = a + (th >> 1);
      const float* ib = &in_s[r * RW + b0];
      const float* wb = &w_s[(kh * 3) * IC * 4];
      for (int ic = 0; ic < IC; ++ic) {
        float4 iv0 = *(const float4*)(ib + ic * IHT * RW);
        if (q == 0) {
          float4 wv = *(const float4*)(wb + (IC + ic) * 4);
          fma16(acc, iv0, wv);
        } else {
          float4 iv4 = *(const float4*)(ib + ic * IHT * RW + 4);
          float4 wv2 = *(const float4*)(wb + (2 * IC + ic) * 4);
          fma16(acc, iv0, wv2);
          float4 sh;
          sh.x = iv0.y; sh.y = iv0.z; sh.z = iv0.w; sh.w = iv4.x;
          float4 wv0 = *(const float4*)(wb + ic * 4);
          fma16(acc, sh, wv0);
        }
      }
    }
    int oh = oh0 + 2 * a + p;
    if (oh >= 300) continue;
#pragma unroll
    for (int b = 0; b < 4; ++b) {
      int ow = 2 * (b0 + b) + q;
      if (ow >= 25) continue;
#pragma unroll
      for (int j = 0; j < 3; ++j)
        out[((long)(nm * 3 + j) * 300 + oh) * 25 + ow] = tanhf(acc[b][j] + c3[j]);
    }
  }
}

// ---------------------------------------------------------------------------
// segmented scan over t
// ---------------------------------------------------------------------------
__global__ __launch_bounds__(256) void scan_kernel(
    const float* __restrict__ dec, const float* __restrict__ x0,
    const unsigned char* __restrict__ z, float* __restrict__ out) {
  int idx = blockIdx.x * 256 + threadIdx.x;
  if (idx >= 256 * 75) return;
  int v = idx % 25;
  int c = (idx / 25) % 3;
  int nm = idx / 75;
  int n = nm >> 1, m = nm & 1;
  const float* db = dec + ((long)(nm * 3 + c) * 300) * 25 + v;
  const unsigned char* zb = z + nm * 300;
  float* ob = out + (((long)(n * 3 + c) * 300) * 25 + v) * 2 + m;
  float x0v = x0[(nm * 3 + c) * 25 + v];
  float carry = 0.f;
  for (int t0 = 0; t0 < 300; t0 += 10) {
    float vals[10];
#pragma unroll
    for (int i = 0; i < 10; ++i) vals[i] = db[(t0 + i) * 25];
#pragma unroll
    for (int i = 0; i < 10; ++i) {
      int t = t0 + i;
      float d = (t == 0) ? x0v : vals[i];
      carry = zb[t] ? 0.f : (d + carry);
      ob[(long)t * 50] = carry;
    }
  }
}

// ---------------------------------------------------------------------------
extern "C" void kernel_launch(void* const* d_in, const int* in_sizes, int n_in,
                              void* d_out, int out_size, void* d_ws, size_t ws_size,
                              hipStream_t stream) {
  const float* x     = (const float*)d_in[0];
  const float* dbn_g = (const float*)d_in[1];
  const float* dbn_b = (const float*)d_in[2];
  const float* c1_w  = (const float*)d_in[3];
  const float* c1_b  = (const float*)d_in[4];
  const float* bn1_g = (const float*)d_in[5];
  const float* bn1_b = (const float*)d_in[6];
  const float* c2_w  = (const float*)d_in[7];
  const float* c2_b  = (const float*)d_in[8];
  const float* bn2_g = (const float*)d_in[9];
  const float* bn2_b = (const float*)d_in[10];
  const float* c3_w  = (const float*)d_in[11];
  const float* c3_b  = (const float*)d_in[12];
  const float* bn3_g = (const float*)d_in[13];
  const float* bn3_b = (const float*)d_in[14];
  const float* fc1_w = (const float*)d_in[15];
  const float* fc1_b = (const float*)d_in[16];
  const float* fc2_w = (const float*)d_in[17];
  const float* fc2_b = (const float*)d_in[18];
  const float* fc3_w = (const float*)d_in[19];
  const float* fc3_b = (const float*)d_in[20];
  const float* fc4_w = (const float*)d_in[21];
  const float* fc4_b = (const float*)d_in[22];
  const float* ct1_w = (const float*)d_in[23];
  const float* ct1_b = (const float*)d_in[24];
  const float* bn4_g = (const float*)d_in[25];
  const float* bn4_b = (const float*)d_in[26];
  const float* ct2_w = (const float*)d_in[27];
  const float* ct2_b = (const float*)d_in[28];
  const float* bn5_g = (const float*)d_in[29];
  const float* bn5_b = (const float*)d_in[30];
  const float* ct3_w = (const float*)d_in[31];
  const float* ct3_b = (const float*)d_in[32];
  float* out = (float*)d_out;

  // ---- workspace (liveness-overlapped arena, ~85.7 MB) ----
  char* ws = (char*)d_ws;
  unsigned char* zbuf = (unsigned char*)ws;             // 76,800
  float* x0 = (float*)(ws + 131072);
  // A (23.2 MB): dm -> wbA(fc1) -> wbA(fc4) -> ct3o
  char* slotA = ws + 262144;
  float* dm   = (float*)slotA;
  u16*   wbA  = (u16*)slotA;
  float* ct3o = (float*)slotA;
  // B (20.97 MB): c1o -> ct2o
  char* slotB = ws + 23461888;
  u16* c1o  = (u16*)slotB;
  u16* ct2o = (u16*)slotB;
  // P (25.8 MB): patch2 halves / patch3 -> partial -> ct1o
  char* slotP = ws + 44433408;
  u16*   patch   = (u16*)slotP;
  float* partial = (float*)slotP;
  u16*   ct1o    = (u16*)slotP;
  // D (8.7 MB): c2o -> f4
  char* slotD = ws + 70254592;
  u16* c2o = (u16*)slotD;
  u16* f4  = (u16*)slotD;
  // E (5 MB): c3o
  u16* c3o = (u16*)(ws + 78954496);
  // G: small buffers
  u16* wb2   = (u16*)(ws + 83968000);
  u16* wb3   = (u16*)(ws + 84230144);
  u16* f1    = (u16*)(ws + 84492288);
  u16* f2    = (u16*)(ws + 85016576);
  u16* f3    = (u16*)(ws + 85082112);
  u16* w2pad = (u16*)(ws + 85606400);
  u16* w3pad = (u16*)(ws + 85630976);

  prep_kernel<<<22500, 256, 0, stream>>>(x, dbn_g, dbn_b, dm, x0);
  zflag_kernel<<<19200, 256, 0, stream>>>(dm, zbuf);

  // conv1 (fp32 dm -> bf16 c1o NCHW)
  conv_tiled_kernel<float, 3, 16, 16, 8, 299, 25, 150, 13, 30, 5>
      <<<dim3(5, 256), 256, 0, stream>>>(dm, c1_w, c1_b, bn1_g, bn1_b, c1o);

  // dm now dead -> cast fc1 weights (permuted to NHWC k-order) into slot A
  wcast_fc1_kernel<<<38912, 256, 0, stream>>>(fc1_w, wbA);
  cast_kernel<<<128, 256, 0, stream>>>(fc2_w, wb2, 32768);
  cast_kernel<<<128, 256, 0, stream>>>(fc3_w, wb3, 32768);
  wpad_kernel<<<48, 256, 0, stream>>>(c2_w, w2pad, 32, 144, 192);
  wpad_kernel<<<80, 256, 0, stream>>>(c3_w, w3pad, 64, 288, 320);

  // conv2 = im2col + MFMA GEMM, two nm-halves (M=67200 each, K=192, N=32)
  for (int h = 0; h < 2; ++h) {
    im2col_kernel<16, 150, 13, 7, 144, 192, false><<<6300, 256, 0, stream>>>(
        c1o, patch, h * 67200, 525, 67200 * 24);
    fc_mfma_kernel<2><<<dim3(1050, 1, 1), 256, 0, stream>>>(
        patch, w2pad, c2_b, bn2_g, bn2_b, c2o + (long)h * 67200 * 32, nullptr,
        192, 32, 192, 32);
  }
  // conv3 = im2col + GEMM (M=38912, K=320, N=64), out NHWC = fc1's A order
  im2col_kernel<32, 75, 7, 4, 288, 320, true><<<6080, 256, 0, stream>>>(
      c2o, patch, 0, 152, 38912 * 40);
  fc_mfma_kernel<2><<<dim3(608, 1, 1), 256, 0, stream>>>(
      patch, w3pad, c3_b, bn3_g, bn3_b, c3o, nullptr, 320, 64, 320, 64);

  // fc1 split-K=8
  fc_mfma_kernel<0><<<dim3(4, 16, 8), 256, 0, stream>>>(
      c3o, wbA, nullptr, nullptr, nullptr, nullptr, partial, 9728, 1024, 1216, 0);
  fc_reduce_kernel<<<256, 256, 0, stream>>>(partial, fc1_b, f1, 262144, 1024, 8);
  cast_kernel<<<9728, 256, 0, stream>>>(fc4_w, wbA, 2490368);
  // fc2 split-K=16
  fc_mfma_kernel<0><<<dim3(4, 2, 16), 256, 0, stream>>>(
      f1, wb2, nullptr, nullptr, nullptr, nullptr, partial, 1024, 128, 64, 0);
  fc_reduce_kernel<<<32, 256, 0, stream>>>(partial, fc2_b, f2, 32768, 128, 16);
  // fc3 split-K=2
  fc_mfma_kernel<0><<<dim3(4, 16, 2), 256, 0, stream>>>(
      f2, wb3, nullptr, nullptr, nullptr, nullptr, partial, 128, 1024, 64, 0);
  fc_reduce_kernel<<<256, 256, 0, stream>>>(partial, fc3_b, f3, 262144, 1024, 2);
  // fc4 direct (N-order = NCHW flat, feeds ct1)
  fc_mfma_kernel<1><<<dim3(4, 152, 1), 256, 0, stream>>>(
      f3, wbA, fc4_b, nullptr, nullptr, f4, nullptr, 1024, 9728, 1024, 9728);

  // decoder: parity-class convT
  convt_cls_kernel<64, 32, 16, 38, 4, 38, 2>
      <<<dim3(4, 256), 256, 0, stream>>>(f4, ct1_w, ct1_b, bn4_g, bn4_b, ct1o);
  convt_cls_kernel<32, 16, 16, 76, 8, 38, 4>
      <<<dim3(4, 256), 256, 0, stream>>>(ct1o, ct2_w, ct2_b, bn5_g, bn5_b, ct2o);
  convt3_cls_kernel<<<dim3(4, 256), 256, 0, stream>>>(ct2o, ct3_w, ct3_b, ct3o);

  scan_kernel<<<75, 256, 0, stream>>>(ct3o, x0, zbuf, out);
}

// Round 6
// 866.856 us; speedup vs baseline: 5.9412x; 1.0229x over previous
//
#include <hip/hip_runtime.h>
#include <math.h>

#define LRELU(y) ((y) > 0.f ? (y) : 0.01f * (y))
__device__ __constant__ float BNS = 0.99999500003749969f; // 1/sqrt(1+1e-5)

typedef unsigned short u16;
typedef __attribute__((ext_vector_type(8))) short bf16x8;
typedef __attribute__((ext_vector_type(4))) float f32x4;

__device__ inline u16 f2b(float f) {
  union { float f; unsigned u; } x; x.f = f;
  return (u16)((x.u + 0x7FFFu + ((x.u >> 16) & 1u)) >> 16);
}
__device__ inline float b2f(u16 b) {
  union { unsigned u; float f; } x; x.u = ((unsigned)b) << 16;
  return x.f;
}
__device__ inline float ldv(const float* p) { return *p; }
__device__ inline float ldv(const u16* p) { return b2f(*p); }

__device__ inline void fma16(float (&acc)[4][4], float4 iv, float4 wv) {
  acc[0][0] += iv.x * wv.x; acc[0][1] += iv.x * wv.y;
  acc[0][2] += iv.x * wv.z; acc[0][3] += iv.x * wv.w;
  acc[1][0] += iv.y * wv.x; acc[1][1] += iv.y * wv.y;
  acc[1][2] += iv.y * wv.z; acc[1][3] += iv.y * wv.w;
  acc[2][0] += iv.z * wv.x; acc[2][1] += iv.z * wv.y;
  acc[2][2] += iv.z * wv.z; acc[2][3] += iv.z * wv.w;
  acc[3][0] += iv.w * wv.x; acc[3][1] += iv.w * wv.y;
  acc[3][2] += iv.w * wv.z; acc[3][3] += iv.w * wv.w;
}

// ---------------------------------------------------------------------------
// cast fp32 -> bf16
// ---------------------------------------------------------------------------
__global__ __launch_bounds__(256) void cast_kernel(
    const float* __restrict__ s, u16* __restrict__ d, int n4) {
  int i = blockIdx.x * 256 + threadIdx.x;
  if (i >= n4) return;
  float4 v = ((const float4*)s)[i];
  ushort4 o;
  o.x = f2b(v.x); o.y = f2b(v.y); o.z = f2b(v.z); o.w = f2b(v.w);
  ((ushort4*)d)[i] = o;
}

// fc1 weight: cast + permute columns k=oc*152+sp -> k'=sp*64+oc
__global__ __launch_bounds__(256) void wcast_fc1_kernel(
    const float* __restrict__ w, u16* __restrict__ wp) {
  int idx = blockIdx.x * 256 + threadIdx.x;
  if (idx >= 1024 * 9728) return;
  int n = idx / 9728, kp = idx % 9728;
  int sp = kp >> 6, oc = kp & 63;
  wp[idx] = f2b(w[(long)n * 9728 + oc * 152 + sp]);
}

// conv weight -> padded bf16 (64 x KP)
__global__ __launch_bounds__(256) void wpad_kernel(
    const float* __restrict__ w, u16* __restrict__ wp, int OC, int K, int KP) {
  int idx = blockIdx.x * 256 + threadIdx.x;
  if (idx >= 64 * KP) return;
  int row = idx / KP, col = idx % KP;
  wp[idx] = (row < OC && col < K) ? f2b(w[row * K + col]) : (u16)0;
}

// ---------------------------------------------------------------------------
// prep: x (128,3,300,25,2) -> dm (256,3,299,25) fp32, x0 (256,3,25) fp32
// ---------------------------------------------------------------------------
__global__ __launch_bounds__(256) void prep_kernel(
    const float* __restrict__ x, const float* __restrict__ g,
    const float* __restrict__ b, float* __restrict__ dm,
    float* __restrict__ x0) {
  int idx = blockIdx.x * 256 + threadIdx.x;
  if (idx >= 256 * 3 * 300 * 25) return;
  int v = idx % 25;
  int t = (idx / 25) % 300;
  int c = (idx / (25 * 300)) % 3;
  int nm = idx / (25 * 300 * 3);
  int n = nm >> 1, m = nm & 1;
  int ch = m * 75 + v * 3 + c;
  float s = g[ch] * BNS, bb = b[ch];
  long xi = (((long)(n * 3 + c) * 300 + t) * 25 + v) * 2 + m;
  float xm_t = x[xi] * s + bb;
  if (t == 0) x0[(nm * 3 + c) * 25 + v] = xm_t;
  if (t < 299) {
    float xm_t1 = x[xi + 50] * s + bb;
    dm[((nm * 3 + c) * 299 + t) * 25 + v] = xm_t1 - xm_t;
  }
}

// ---------------------------------------------------------------------------
// z flags: one wave per (nm,t)
// ---------------------------------------------------------------------------
__global__ __launch_bounds__(256) void zflag_kernel(
    const float* __restrict__ dm, unsigned char* __restrict__ z) {
  int gw = blockIdx.x * 4 + (threadIdx.x >> 6);
  if (gw >= 256 * 300) return;
  int lane = threadIdx.x & 63;
  int t = gw % 300, nm = gw / 300;
  bool nz = false;
  if (t < 299) {
    const float* base = dm + (long)nm * 3 * 299 * 25 + t * 25;
    if (lane < 75) {
      int c = lane / 25, v = lane % 25;
      nz = base[c * 299 * 25 + v] != 0.f;
    }
    int l2 = lane + 64;
    if (l2 < 75) {
      int c = l2 / 25, v = l2 % 25;
      nz = nz || (base[c * 299 * 25 + v] != 0.f);
    }
  }
  unsigned long long mask = __ballot(nz);
  if (lane == 0) z[nm * 300 + t] = (unsigned char)((t < 299) && (mask == 0ull));
}

// ---------------------------------------------------------------------------
// conv1 (VALU tiled, fp32 in, bf16 out)
// ---------------------------------------------------------------------------
template <typename TI, int IC, int OC, int OCB, int ACC, int H, int W, int OH,
          int OW, int TOH, int NTILE>
__global__ __launch_bounds__(256) void conv_tiled_kernel(
    const TI* __restrict__ in, const float* __restrict__ w,
    const float* __restrict__ cb, const float* __restrict__ bg,
    const float* __restrict__ bnb, u16* __restrict__ out) {
  constexpr int IHT = 2 * TOH + 1;
  constexpr int RL = W + 2;
  __shared__ float in_s[IC * IHT * RL];
  __shared__ float w_s[9 * IC * OCB];
  int bx = blockIdx.x;
  int nm = blockIdx.y;
  int tile = bx % NTILE;
  int oc0 = (bx / NTILE) * OCB;
  int oh0 = tile * TOH;
  int ih0 = 2 * oh0 - 1;
  const TI* inb = in + (long)nm * IC * H * W;
  for (int e = threadIdx.x; e < IC * IHT * RL; e += 256) {
    int c = e % RL;
    int r = (e / RL) % IHT;
    int ic = e / (RL * IHT);
    int ih = ih0 + r, iw = c - 1;
    float v = 0.f;
    if (ih >= 0 && ih < H && iw >= 0 && iw < W) v = ldv(&inb[(ic * H + ih) * W + iw]);
    in_s[e] = v;
  }
  for (int e = threadIdx.x; e < 9 * IC * OCB; e += 256) {
    int ocl = e % OCB;
    int ic = (e / OCB) % IC;
    int khw = e / (OCB * IC);
    int kh = khw / 3, kw = khw % 3;
    w_s[e] = w[(((oc0 + ocl) * IC + ic) * 3 + kh) * 3 + kw];
  }
  __syncthreads();
  constexpr int NPOS = TOH * OW;
  constexpr int NWI = NPOS * (OCB / ACC);
  for (int wi = threadIdx.x; wi < NWI; wi += 256) {
    int pos = wi % NPOS;
    int jb = (wi / NPOS) * ACC;
    int ow = pos % OW;
    int oh_l = pos / OW;
    int oh = oh0 + oh_l;
    if (oh >= OH) continue;
    float acc[ACC];
#pragma unroll
    for (int j = 0; j < ACC; ++j) acc[j] = 0.f;
    for (int kh = 0; kh < 3; ++kh) {
      int r = 2 * oh_l + kh;
      for (int kw = 0; kw < 3; ++kw) {
        int cc = 2 * ow + kw;
        const float* ip = &in_s[r * RL + cc];
        const float* wp = &w_s[(kh * 3 + kw) * IC * OCB + jb];
        for (int ic = 0; ic < IC; ++ic) {
          float a = ip[ic * IHT * RL];
#pragma unroll
          for (int j = 0; j < ACC; ++j) acc[j] += a * wp[ic * OCB + j];
        }
      }
    }
#pragma unroll
    for (int j = 0; j < ACC; ++j) {
      int oc = oc0 + jb + j;
      float y = (acc[j] + cb[oc]) * (bg[oc] * BNS) + bnb[oc];
      out[((long)nm * OC + oc) * OH * OW + oh * OW + ow] = f2b(LRELU(y));
    }
  }
}

// ---------------------------------------------------------------------------
// im2col: build bf16 patch (m, KP), stride-2, pad 1, 3x3.
// ---------------------------------------------------------------------------
template <int IC, int H, int W, int OWW, int K, int KP, bool NHWC>
__global__ __launch_bounds__(256) void im2col_kernel(
    const u16* __restrict__ in, u16* __restrict__ patch, int m_off,
    int spatial, int n_threads) {
  int idx = blockIdx.x * 256 + threadIdx.x;
  if (idx >= n_threads) return;
  constexpr int KP8 = KP / 8;
  int m = idx / KP8;
  int k0 = (idx % KP8) * 8;
  int gm = m_off + m;
  int nm = gm / spatial, sp = gm % spatial;
  int oh = sp / OWW, ow = sp % OWW;
  __align__(16) u16 vals[8];
#pragma unroll
  for (int j = 0; j < 8; ++j) {
    int k = k0 + j;
    u16 v = 0;
    if (k < K) {
      int ic = k / 9, tap = k % 9;
      int ih = 2 * oh + tap / 3 - 1, iw = 2 * ow + tap % 3 - 1;
      if ((unsigned)ih < (unsigned)H && (unsigned)iw < (unsigned)W)
        v = NHWC ? in[((long)nm * H * W + ih * W + iw) * IC + ic]
                 : in[((long)nm * IC + ic) * H * W + ih * W + iw];
    }
    vals[j] = v;
  }
  *(uint4*)(patch + (long)m * KP + k0) = *(uint4*)vals;
}

// ---------------------------------------------------------------------------
// MFMA GEMM: out[m][n] = epilogue(sum_k A[m][k]*Wt[n][k]).
// EPI: 0=split-K fp32 partial; 1=bias+lrelu bf16; 2=conv BN+lrelu bf16
// ---------------------------------------------------------------------------
template <int EPI>
__global__ __launch_bounds__(256) void fc_mfma_kernel(
    const u16* __restrict__ A, const u16* __restrict__ Wt,
    const float* __restrict__ p0, const float* __restrict__ p1,
    const float* __restrict__ p2, u16* __restrict__ out,
    float* __restrict__ partial, int K, int N, int ksegLen, int nvalid) {
  __shared__ u16 As[64][72];
  __shared__ u16 Bs[64][72];
  int tid = threadIdx.x;
  int m0 = blockIdx.x * 64, n0 = blockIdx.y * 64;
  long kbase = (long)blockIdx.z * ksegLen;
  int row = tid >> 3;
  int seg = (tid & 7) * 8;
  const u16* ap0 = A + (long)(m0 + row) * K + kbase + seg;
  const u16* ap1 = A + (long)(m0 + row + 32) * K + kbase + seg;
  const u16* bp0 = Wt + (long)(n0 + row) * K + kbase + seg;
  const u16* bp1 = Wt + (long)(n0 + row + 32) * K + kbase + seg;
  uint4 ra0 = *(const uint4*)ap0;
  uint4 ra1 = *(const uint4*)ap1;
  uint4 rb0 = *(const uint4*)bp0;
  uint4 rb1 = *(const uint4*)bp1;
  int wv = tid >> 6, lane = tid & 63;
  int lr = lane & 15, q = lane >> 4;
  int mb = (wv >> 1) * 32, nb = (wv & 1) * 32;
  f32x4 acc[2][2] = {};
  for (int k0 = 0; k0 < ksegLen; k0 += 64) {
    *(uint4*)&As[row][seg] = ra0;
    *(uint4*)&As[row + 32][seg] = ra1;
    *(uint4*)&Bs[row][seg] = rb0;
    *(uint4*)&Bs[row + 32][seg] = rb1;
    __syncthreads();
    if (k0 + 64 < ksegLen) {
      ra0 = *(const uint4*)(ap0 + k0 + 64);
      ra1 = *(const uint4*)(ap1 + k0 + 64);
      rb0 = *(const uint4*)(bp0 + k0 + 64);
      rb1 = *(const uint4*)(bp1 + k0 + 64);
    }
#pragma unroll
    for (int kk = 0; kk < 64; kk += 32) {
      bf16x8 a0 = *(bf16x8*)&As[mb + lr][kk + q * 8];
      bf16x8 a1 = *(bf16x8*)&As[mb + 16 + lr][kk + q * 8];
      bf16x8 b0 = *(bf16x8*)&Bs[nb + lr][kk + q * 8];
      bf16x8 b1 = *(bf16x8*)&Bs[nb + 16 + lr][kk + q * 8];
      acc[0][0] = __builtin_amdgcn_mfma_f32_16x16x32_bf16(a0, b0, acc[0][0], 0, 0, 0);
      acc[0][1] = __builtin_amdgcn_mfma_f32_16x16x32_bf16(a0, b1, acc[0][1], 0, 0, 0);
      acc[1][0] = __builtin_amdgcn_mfma_f32_16x16x32_bf16(a1, b0, acc[1][0], 0, 0, 0);
      acc[1][1] = __builtin_amdgcn_mfma_f32_16x16x32_bf16(a1, b1, acc[1][1], 0, 0, 0);
    }
    __syncthreads();
  }
#pragma unroll
  for (int mi = 0; mi < 2; ++mi)
#pragma unroll
    for (int ni = 0; ni < 2; ++ni) {
      int col = n0 + nb + ni * 16 + lr;
      if (EPI == 2 && col >= nvalid) continue;
      float b0v = 0.f, scv = 1.f, shv = 0.f;
      if (EPI == 1) b0v = p0[col];
      if (EPI == 2) { b0v = p0[col]; scv = p1[col] * BNS; shv = p2[col]; }
#pragma unroll
      for (int r = 0; r < 4; ++r) {
        int grow = m0 + mb + mi * 16 + q * 4 + r;
        float y = acc[mi][ni][r];
        if (EPI == 0) {
          partial[((long)blockIdx.z * 256 + grow) * N + col] = y;
        } else if (EPI == 1) {
          out[(long)grow * N + col] = f2b(LRELU(y + b0v));
        } else {
          out[(long)grow * N + col] = f2b(LRELU((y + b0v) * scv + shv));
        }
      }
    }
}

// ---------------------------------------------------------------------------
// split-K reduce
// ---------------------------------------------------------------------------
__global__ __launch_bounds__(256) void fc_reduce_kernel(
    const float* __restrict__ partial, const float* __restrict__ bias,
    u16* __restrict__ out, int MN, int N, int S) {
  int i = blockIdx.x * 256 + threadIdx.x;
  if (i * 4 >= MN) return;
  float4 s = ((const float4*)partial)[i];
  for (int t = 1; t < S; ++t) {
    float4 p = ((const float4*)partial)[(long)t * (MN >> 2) + i];
    s.x += p.x; s.y += p.y; s.z += p.z; s.w += p.w;
  }
  int col = (i * 4) % N;
  float4 bv = *(const float4*)(bias + col);
  ushort4 o;
  o.x = f2b(LRELU(s.x + bv.x));
  o.y = f2b(LRELU(s.y + bv.y));
  o.z = f2b(LRELU(s.z + bv.z));
  o.w = f2b(LRELU(s.w + bv.w));
  ((ushort4*)out)[i] = o;
}

// ---------------------------------------------------------------------------
// Transposed conv via parity classes — WAVE-UNIFORM class (wave = class).
// 4 waves/block = 4 (p,q) classes; lane strides rem within class.
// 4x4 (spatial x oc) register tile, float4 LDS reads, fused BN+lrelu.
// grid: (NTILEH * OCTOT/OCB, 256)
// ---------------------------------------------------------------------------
template <int IC, int OCTOT, int OCB, int IH, int IW, int TOH, int NTILEH>
__global__ __launch_bounds__(256) void convt_cls_kernel(
    const u16* __restrict__ in, const float* __restrict__ w,
    const float* __restrict__ cb, const float* __restrict__ bg,
    const float* __restrict__ bnb, u16* __restrict__ out) {
  constexpr int AA = TOH / 2;
  constexpr int IHT = AA + 1;
  constexpr int RW = IW + 4;
  constexpr int OH = 2 * IH, OW = 2 * IW;
  constexpr int BG = IW / 4;
  constexpr int OG = OCB / 4;
  constexpr int CLS = AA * BG * OG;
  __shared__ float in_s[IC * IHT * RW];
  __shared__ float w_s[9 * IC * OCB];
  int nm = blockIdx.y;
  int tile = blockIdx.x % NTILEH;
  int oc0 = (blockIdx.x / NTILEH) * OCB;
  int oh0 = tile * TOH;
  int ihb = oh0 >> 1;
  const u16* inb = in + (long)nm * IC * IH * IW;
  for (int e = threadIdx.x; e < IC * IHT * RW; e += 256) {
    int cw = e % RW;
    int r = (e / RW) % IHT;
    int ic = e / (RW * IHT);
    int ih = ihb + r;
    float v = 0.f;
    if (cw < IW && ih < IH) v = b2f(inb[(ic * IH + ih) * IW + cw]);
    in_s[e] = v;
  }
  for (int e = threadIdx.x; e < 9 * IC * OCB; e += 256) {
    int ocl = e % OCB;
    int ic = (e / OCB) % IC;
    int khw = e / (OCB * IC);
    w_s[e] = w[(ic * OCTOT + oc0 + ocl) * 9 + khw];
  }
  __syncthreads();
  int cls = threadIdx.x >> 6;  // wave-uniform class
  int lane = threadIdx.x & 63;
  int p = cls >> 1, q = cls & 1;
  for (int rem = lane; rem < CLS; rem += 64) {
    int a = rem % AA;
    int t2 = rem / AA;
    int bgi = t2 % BG;
    int og = t2 / BG;
    int b0 = bgi * 4, oc = og * 4;
    float acc[4][4] = {};
    for (int kh = 0; kh < 3; ++kh) {
      int th = p + 1 - kh;
      if (th & 1) continue;  // wave-uniform
      int r = a + (th >> 1);
      const float* ib = &in_s[r * RW + b0];
      const float* wb = &w_s[(kh * 3) * IC * OCB + oc];
      for (int ic = 0; ic < IC; ++ic) {
        float4 iv0 = *(const float4*)(ib + ic * IHT * RW);
        if (q == 0) {
          float4 wv = *(const float4*)(wb + (IC + ic) * OCB);  // kw=1
          fma16(acc, iv0, wv);
        } else {
          float4 iv4 = *(const float4*)(ib + ic * IHT * RW + 4);
          float4 wv2 = *(const float4*)(wb + (2 * IC + ic) * OCB);  // kw=2
          fma16(acc, iv0, wv2);
          float4 sh;
          sh.x = iv0.y; sh.y = iv0.z; sh.z = iv0.w; sh.w = iv4.x;
          float4 wv0 = *(const float4*)(wb + ic * OCB);  // kw=0
          fma16(acc, sh, wv0);
        }
      }
    }
    int oh = oh0 + 2 * a + p;
    if (oh >= OH) continue;
    float cc[4], ss[4], hh[4];
#pragma unroll
    for (int j = 0; j < 4; ++j) {
      int o = oc0 + oc + j;
      cc[j] = cb[o]; ss[j] = bg[o] * BNS; hh[j] = bnb[o];
    }
#pragma unroll
    for (int b = 0; b < 4; ++b) {
      int ow = 2 * (b0 + b) + q;
#pragma unroll
      for (int j = 0; j < 4; ++j) {
        float y = (acc[b][j] + cc[j]) * ss[j] + hh[j];
        out[((long)(nm * OCTOT + oc0 + oc + j) * OH + oh) * OW + ow] =
            f2b(LRELU(y));
      }
    }
  }
}

// ---------------------------------------------------------------------------
// ct3 parity-class, wave-uniform class: 16->3, tanh, fp32 out (256,3,300,25)
// grid (4, 256)
// ---------------------------------------------------------------------------
__global__ __launch_bounds__(256) void convt3_cls_kernel(
    const u16* __restrict__ in, const float* __restrict__ w,
    const float* __restrict__ cb, float* __restrict__ out) {
  constexpr int IC = 16, IH = 152, IW = 16, TOH = 76;
  constexpr int AA = 38, IHT = 39, RW = 20, BG = 4, CLS = AA * BG;
  __shared__ float in_s[IC * IHT * RW];
  __shared__ float w_s[9 * IC * 4];
  int nm = blockIdx.y;
  int oh0 = blockIdx.x * TOH;
  int ihb = oh0 >> 1;
  const u16* inb = in + (long)nm * IC * IH * IW;
  for (int e = threadIdx.x; e < IC * IHT * RW; e += 256) {
    int cw = e % RW;
    int r = (e / RW) % IHT;
    int ic = e / (RW * IHT);
    int ih = ihb + r;
    float v = 0.f;
    if (cw < IW && ih < IH) v = b2f(inb[(ic * IH + ih) * IW + cw]);
    in_s[e] = v;
  }
  for (int e = threadIdx.x; e < 9 * IC * 4; e += 256) {
    int ocl = e % 4;
    int ic = (e / 4) % IC;
    int khw = e / 64;
    w_s[e] = (ocl < 3) ? w[(ic * 3 + ocl) * 9 + khw] : 0.f;
  }
  __syncthreads();
  float c3[3] = {cb[0], cb[1], cb[2]};
  int cls = threadIdx.x >> 6;  // wave-uniform class
  int lane = threadIdx.x & 63;
  int p = cls >> 1, q = cls & 1;
  for (int rem = lane; rem < CLS; rem += 64) {
    int a = rem % AA;
    int bgi = rem / AA;
    int b0 = bgi * 4;
    float acc[4][4] = {};
    for (int kh = 0; kh < 3; ++kh) {
      int th = p + 1 - kh;
      if (th & 1) continue;  // wave-uniform
      int r = a + (th >> 1);
      const float* ib = &in_s[r * RW + b0];
      const float* wb = &w_s[(kh * 3) * IC * 4];
      for (int ic = 0; ic < IC; ++ic) {
        float4 iv0 = *(const float4*)(ib + ic * IHT * RW);
        if (q == 0) {
          float4 wv = *(const float4*)(wb + (IC + ic) * 4);
          fma16(acc, iv0, wv);
        } else {
          float4 iv4 = *(const float4*)(ib + ic * IHT * RW + 4);
          float4 wv2 = *(const float4*)(wb + (2 * IC + ic) * 4);
          fma16(acc, iv0, wv2);
          float4 sh;
          sh.x = iv0.y; sh.y = iv0.z; sh.z = iv0.w; sh.w = iv4.x;
          float4 wv0 = *(const float4*)(wb + ic * 4);
          fma16(acc, sh, wv0);
        }
      }
    }
    int oh = oh0 + 2 * a + p;
    if (oh >= 300) continue;
#pragma unroll
    for (int b = 0; b < 4; ++b) {
      int ow = 2 * (b0 + b) + q;
      if (ow >= 25) continue;
#pragma unroll
      for (int j = 0; j < 3; ++j)
        out[((long)(nm * 3 + j) * 300 + oh) * 25 + ow] = tanhf(acc[b][j] + c3[j]);
    }
  }
}

// ---------------------------------------------------------------------------
// segmented scan over t
// ---------------------------------------------------------------------------
__global__ __launch_bounds__(256) void scan_kernel(
    const float* __restrict__ dec, const float* __restrict__ x0,
    const unsigned char* __restrict__ z, float* __restrict__ out) {
  int idx = blockIdx.x * 256 + threadIdx.x;
  if (idx >= 256 * 75) return;
  int v = idx % 25;
  int c = (idx / 25) % 3;
  int nm = idx / 75;
  int n = nm >> 1, m = nm & 1;
  const float* db = dec + ((long)(nm * 3 + c) * 300) * 25 + v;
  const unsigned char* zb = z + nm * 300;
  float* ob = out + (((long)(n * 3 + c) * 300) * 25 + v) * 2 + m;
  float x0v = x0[(nm * 3 + c) * 25 + v];
  float carry = 0.f;
  for (int t0 = 0; t0 < 300; t0 += 10) {
    float vals[10];
#pragma unroll
    for (int i = 0; i < 10; ++i) vals[i] = db[(t0 + i) * 25];
#pragma unroll
    for (int i = 0; i < 10; ++i) {
      int t = t0 + i;
      float d = (t == 0) ? x0v : vals[i];
      carry = zb[t] ? 0.f : (d + carry);
      ob[(long)t * 50] = carry;
    }
  }
}

// ---------------------------------------------------------------------------
extern "C" void kernel_launch(void* const* d_in, const int* in_sizes, int n_in,
                              void* d_out, int out_size, void* d_ws, size_t ws_size,
                              hipStream_t stream) {
  const float* x     = (const float*)d_in[0];
  const float* dbn_g = (const float*)d_in[1];
  const float* dbn_b = (const float*)d_in[2];
  const float* c1_w  = (const float*)d_in[3];
  const float* c1_b  = (const float*)d_in[4];
  const float* bn1_g = (const float*)d_in[5];
  const float* bn1_b = (const float*)d_in[6];
  const float* c2_w  = (const float*)d_in[7];
  const float* c2_b  = (const float*)d_in[8];
  const float* bn2_g = (const float*)d_in[9];
  const float* bn2_b = (const float*)d_in[10];
  const float* c3_w  = (const float*)d_in[11];
  const float* c3_b  = (const float*)d_in[12];
  const float* bn3_g = (const float*)d_in[13];
  const float* bn3_b = (const float*)d_in[14];
  const float* fc1_w = (const float*)d_in[15];
  const float* fc1_b = (const float*)d_in[16];
  const float* fc2_w = (const float*)d_in[17];
  const float* fc2_b = (const float*)d_in[18];
  const float* fc3_w = (const float*)d_in[19];
  const float* fc3_b = (const float*)d_in[20];
  const float* fc4_w = (const float*)d_in[21];
  const float* fc4_b = (const float*)d_in[22];
  const float* ct1_w = (const float*)d_in[23];
  const float* ct1_b = (const float*)d_in[24];
  const float* bn4_g = (const float*)d_in[25];
  const float* bn4_b = (const float*)d_in[26];
  const float* ct2_w = (const float*)d_in[27];
  const float* ct2_b = (const float*)d_in[28];
  const float* bn5_g = (const float*)d_in[29];
  const float* bn5_b = (const float*)d_in[30];
  const float* ct3_w = (const float*)d_in[31];
  const float* ct3_b = (const float*)d_in[32];
  float* out = (float*)d_out;

  // ---- workspace (liveness-overlapped arena, ~85.7 MB) ----
  char* ws = (char*)d_ws;
  unsigned char* zbuf = (unsigned char*)ws;             // 76,800
  float* x0 = (float*)(ws + 131072);
  // A (23.2 MB): dm -> wbA(fc1) -> wbA(fc4) -> ct3o
  char* slotA = ws + 262144;
  float* dm   = (float*)slotA;
  u16*   wbA  = (u16*)slotA;
  float* ct3o = (float*)slotA;
  // B (20.97 MB): c1o -> ct2o
  char* slotB = ws + 23461888;
  u16* c1o  = (u16*)slotB;
  u16* ct2o = (u16*)slotB;
  // P (25.8 MB): patch2 halves / patch3 -> partial -> ct1o
  char* slotP = ws + 44433408;
  u16*   patch   = (u16*)slotP;
  float* partial = (float*)slotP;
  u16*   ct1o    = (u16*)slotP;
  // D (8.7 MB): c2o -> f4
  char* slotD = ws + 70254592;
  u16* c2o = (u16*)slotD;
  u16* f4  = (u16*)slotD;
  // E (5 MB): c3o
  u16* c3o = (u16*)(ws + 78954496);
  // G: small buffers
  u16* wb2   = (u16*)(ws + 83968000);
  u16* wb3   = (u16*)(ws + 84230144);
  u16* f1    = (u16*)(ws + 84492288);
  u16* f2    = (u16*)(ws + 85016576);
  u16* f3    = (u16*)(ws + 85082112);
  u16* w2pad = (u16*)(ws + 85606400);
  u16* w3pad = (u16*)(ws + 85630976);

  prep_kernel<<<22500, 256, 0, stream>>>(x, dbn_g, dbn_b, dm, x0);
  zflag_kernel<<<19200, 256, 0, stream>>>(dm, zbuf);

  // conv1 (fp32 dm -> bf16 c1o NCHW)
  conv_tiled_kernel<float, 3, 16, 16, 8, 299, 25, 150, 13, 30, 5>
      <<<dim3(5, 256), 256, 0, stream>>>(dm, c1_w, c1_b, bn1_g, bn1_b, c1o);

  // dm now dead -> cast fc1 weights (permuted to NHWC k-order) into slot A
  wcast_fc1_kernel<<<38912, 256, 0, stream>>>(fc1_w, wbA);
  cast_kernel<<<128, 256, 0, stream>>>(fc2_w, wb2, 32768);
  cast_kernel<<<128, 256, 0, stream>>>(fc3_w, wb3, 32768);
  wpad_kernel<<<48, 256, 0, stream>>>(c2_w, w2pad, 32, 144, 192);
  wpad_kernel<<<80, 256, 0, stream>>>(c3_w, w3pad, 64, 288, 320);

  // conv2 = im2col + MFMA GEMM, two nm-halves (M=67200 each, K=192, N=32)
  for (int h = 0; h < 2; ++h) {
    im2col_kernel<16, 150, 13, 7, 144, 192, false><<<6300, 256, 0, stream>>>(
        c1o, patch, h * 67200, 525, 67200 * 24);
    fc_mfma_kernel<2><<<dim3(1050, 1, 1), 256, 0, stream>>>(
        patch, w2pad, c2_b, bn2_g, bn2_b, c2o + (long)h * 67200 * 32, nullptr,
        192, 32, 192, 32);
  }
  // conv3 = im2col + GEMM (M=38912, K=320, N=64), out NHWC = fc1's A order
  im2col_kernel<32, 75, 7, 4, 288, 320, true><<<6080, 256, 0, stream>>>(
      c2o, patch, 0, 152, 38912 * 40);
  fc_mfma_kernel<2><<<dim3(608, 1, 1), 256, 0, stream>>>(
      patch, w3pad, c3_b, bn3_g, bn3_b, c3o, nullptr, 320, 64, 320, 64);

  // fc1 split-K=8
  fc_mfma_kernel<0><<<dim3(4, 16, 8), 256, 0, stream>>>(
      c3o, wbA, nullptr, nullptr, nullptr, nullptr, partial, 9728, 1024, 1216, 0);
  fc_reduce_kernel<<<256, 256, 0, stream>>>(partial, fc1_b, f1, 262144, 1024, 8);
  cast_kernel<<<9728, 256, 0, stream>>>(fc4_w, wbA, 2490368);
  // fc2 split-K=16
  fc_mfma_kernel<0><<<dim3(4, 2, 16), 256, 0, stream>>>(
      f1, wb2, nullptr, nullptr, nullptr, nullptr, partial, 1024, 128, 64, 0);
  fc_reduce_kernel<<<32, 256, 0, stream>>>(partial, fc2_b, f2, 32768, 128, 16);
  // fc3 split-K=2
  fc_mfma_kernel<0><<<dim3(4, 16, 2), 256, 0, stream>>>(
      f2, wb3, nullptr, nullptr, nullptr, nullptr, partial, 128, 1024, 64, 0);
  fc_reduce_kernel<<<256, 256, 0, stream>>>(partial, fc3_b, f3, 262144, 1024, 2);
  // fc4 direct (N-order = NCHW flat, feeds ct1)
  fc_mfma_kernel<1><<<dim3(4, 152, 1), 256, 0, stream>>>(
      f3, wbA, fc4_b, nullptr, nullptr, f4, nullptr, 1024, 9728, 1024, 9728);

  // decoder: parity-class convT (wave-uniform classes)
  convt_cls_kernel<64, 32, 16, 38, 4, 38, 2>
      <<<dim3(4, 256), 256, 0, stream>>>(f4, ct1_w, ct1_b, bn4_g, bn4_b, ct1o);
  convt_cls_kernel<32, 16, 16, 76, 8, 38, 4>
      <<<dim3(4, 256), 256, 0, stream>>>(ct1o, ct2_w, ct2_b, bn5_g, bn5_b, ct2o);
  convt3_cls_kernel<<<dim3(4, 256), 256, 0, stream>>>(ct2o, ct3_w, ct3_b, ct3o);

  scan_kernel<<<75, 256, 0, stream>>>(ct3o, x0, zbuf, out);
}